// Round 7
// baseline (1093.962 us; speedup 1.0000x reference)
//
#include <hip/hip_runtime.h>

// ---------------- problem constants ----------------
#define S_LEN   2048
#define NH      16
#define DIM     2048
#define KD      2048
#define VD      2048
#define MB      1048576ull
#define CT      64     // chunk length
#define NC      32     // chunks per sequence

typedef short  short8  __attribute__((ext_vector_type(8)));
typedef short  short4v __attribute__((ext_vector_type(4)));
typedef float  floatx4 __attribute__((ext_vector_type(4)));

#define MFMA(a, b, c) __builtin_amdgcn_mfma_f32_16x16x32_bf16((a), (b), (c), 0, 0, 0)

// fp32 -> bf16, round-to-nearest-even
__device__ inline short f2bf(float x) {
    unsigned u = __float_as_uint(x);
    unsigned r = (u + 0x7fffu + ((u >> 16) & 1u)) >> 16;
    return (short)r;
}
__device__ inline float bf2f(short s) {
    return __uint_as_float(((unsigned)(unsigned short)s) << 16);
}
__device__ inline float silu_f(float x) { return x / (1.f + __expf(-x)); }

__device__ inline short8 neg8(short8 a) {
    unsigned* p = (unsigned*)&a;
    p[0] ^= 0x80008000u; p[1] ^= 0x80008000u;
    p[2] ^= 0x80008000u; p[3] ^= 0x80008000u;
    return a;
}

// async global->LDS, 16B per lane; LDS dest is wave-uniform base (+lane*16 implicit)
__device__ inline void load_lds16(const void* g, void* l) {
    __builtin_amdgcn_global_load_lds(
        (const __attribute__((address_space(1))) unsigned int*)g,
        (__attribute__((address_space(3))) unsigned int*)l, 16, 0, 0);
}

__device__ inline void store_c(float* C, size_t idx, float v) { C[idx] = v; }
__device__ inline void store_c(short* C, size_t idx, float v) { C[idx] = f2bf(v); }

// LDS-only barrier (no vmcnt drain)
__device__ __forceinline__ void lds_barrier() {
    asm volatile("s_waitcnt lgkmcnt(0)" ::: "memory");
    __builtin_amdgcn_s_barrier();
}

// Boundary barrier for the GEMM pipeline: lgkmcnt(0) before s_barrier guarantees every
// wave's issued ds_reads of the retiring buffer completed before any wave can DMA over
// it (cross-wave WAR).  Memory-clobber asm on both sides pins LDS ops against motion
// across the barrier.
__device__ __forceinline__ void boundary_barrier() {
    asm volatile("s_waitcnt lgkmcnt(0)" ::: "memory");
    __builtin_amdgcn_s_barrier();
    asm volatile("" ::: "memory");
}

#define VM(n_) asm volatile("s_waitcnt vmcnt(" #n_ ")" ::: "memory");

// ---------------- fp32 -> bf16 conversion (all 6 tensors, one launch) ----------------
__global__ __launch_bounds__(256) void cvt_all_kernel(
    const float* __restrict__ x,  const float* __restrict__ Wq,
    const float* __restrict__ Wk, const float* __restrict__ Wv,
    const float* __restrict__ Wg, const float* __restrict__ Wo,
    short* __restrict__ xb,  short* __restrict__ Wqb, short* __restrict__ Wkb,
    short* __restrict__ Wvb, short* __restrict__ Wgb, short* __restrict__ Wob) {
    const float* in; short* out; int n8;
    switch (blockIdx.y) {
        case 0:  in = x;  out = xb;  n8 = 1048576; break;
        case 1:  in = Wq; out = Wqb; n8 = 524288;  break;
        case 2:  in = Wk; out = Wkb; n8 = 524288;  break;
        case 3:  in = Wv; out = Wvb; n8 = 524288;  break;
        case 4:  in = Wg; out = Wgb; n8 = 524288;  break;
        default: in = Wo; out = Wob; n8 = 524288;  break;
    }
    int i = blockIdx.x * 256 + threadIdx.x;
    if (i >= n8) return;
    float4 a = ((const float4*)in)[2 * i];
    float4 b = ((const float4*)in)[2 * i + 1];
    short8 o;
    o[0] = f2bf(a.x); o[1] = f2bf(a.y); o[2] = f2bf(a.z); o[3] = f2bf(a.w);
    o[4] = f2bf(b.x); o[5] = f2bf(b.y); o[6] = f2bf(b.z); o[7] = f2bf(b.w);
    ((short8*)out)[i] = o;
}

// ---------------- 256^2 bf16 GEMM, register-fragment-prefetch pipeline ----------------
// (R5, verified: 1 barrier/sub-tile, frag prefetch 1 phase ahead, counted vmcnt(8);
//  swizzle chunk ^= (row>>1)&3, conflicts == 0 measured R4.)

#define STAGE8(s_, isB_)                                                     \
    {                                                                        \
        const char* gsrc = (isB_) ? (const char*)Bw : (const char*)A;        \
        int t0 = (isB_) ? n0 : m0;                                           \
        char* dbase = smem + ((s_) & 3) * 32768 + (isB_) * 16384;            \
        _Pragma("unroll")                                                    \
        for (int ld = 0; ld < 2; ++ld) {                                     \
            int ch = ld * 8 + wave;                                          \
            int Pl = (ch << 10) + (lane << 4);                               \
            int Q  = Pl ^ (((lane >> 3) & 3) << 4);                          \
            const char* src = gsrc + ((size_t)(t0 + (Q >> 6)) << 12)         \
                              + ((size_t)(s_) << 6) + (Q & 63);              \
            load_lds16(src, dbase + (ch << 10));                             \
        }                                                                    \
    }

#define RD_AF(dst_, s_, qm_)                                                 \
    {                                                                        \
        const char* sb_ = smem + ((s_) & 3) * 32768;                         \
        _Pragma("unroll")                                                    \
        for (int mf = 0; mf < 4; ++mf)                                       \
            dst_[mf] = *(const short8*)(sb_ +                                \
                ((rowA_base + (qm_) * 64 + mf * 16) << 6) + qsw);            \
    }

#define RD_BF(dst_, s_)                                                      \
    {                                                                        \
        const char* sb_ = smem + ((s_) & 3) * 32768 + 16384;                 \
        _Pragma("unroll")                                                    \
        for (int nf = 0; nf < 4; ++nf)                                       \
            dst_[nf] = *(const short8*)(sb_ +                                \
                ((rowB_base + nf * 16) << 6) + qsw);                         \
    }

#define MM(qm_, af_, bf_)                                                    \
    {                                                                        \
        __builtin_amdgcn_s_setprio(1);                                       \
        _Pragma("unroll")                                                    \
        for (int mf = 0; mf < 4; ++mf)                                       \
            _Pragma("unroll")                                                \
            for (int nf = 0; nf < 4; ++nf)                                   \
                acc[(qm_) * 4 + mf][nf] =                                    \
                    MFMA(af_[mf], bf_[nf], acc[(qm_) * 4 + mf][nf]);         \
        __builtin_amdgcn_s_setprio(0);                                       \
    }

template <typename OutT>
__device__ __forceinline__ void gemm8_tile(const short* __restrict__ A,
                                           const short* __restrict__ Bw,
                                           OutT* __restrict__ C, char* smem) {
    int x  = blockIdx.x;
    int xs = (x & 7) * 16 + (x >> 3);            // XCD-chunked swizzle (128 % 8 == 0)
    int m0 = (xs >> 3) * 256;                    // 16 m-tiles
    int n0 = (xs & 7) * 256;                     // 8 n-tiles
    int tid  = threadIdx.x;
    int wave = tid >> 6, lane = tid & 63;
    int l16  = lane & 15, quad = lane >> 4;
    int wm = wave >> 2, wn = wave & 3;
    int qsw = ((quad ^ ((l16 >> 1) & 3)) << 4);  // read-side swizzled 16B-chunk offset
    int rowA_base = wm * 128 + l16;
    int rowB_base = wn * 64 + l16;

    floatx4 acc[8][4];
#pragma unroll
    for (int i = 0; i < 8; ++i)
#pragma unroll
        for (int j = 0; j < 4; ++j) acc[i][j] = (floatx4){0.f, 0.f, 0.f, 0.f};
    short8 af0[4], af1[4], bfA[4], bfB[4];

    // prologue: stage sub-tiles 0,1,2; drain s0; publish; prefetch first fragments
    STAGE8(0, 0) STAGE8(0, 1)
    STAGE8(1, 0) STAGE8(1, 1)
    STAGE8(2, 0) STAGE8(2, 1)
    VM(8)
    boundary_barrier();
    RD_AF(af0, 0, 0) RD_BF(bfA, 0)

    // steady state: sub-tiles 0..59, unrolled x2 for bfA/bfB parity
#pragma unroll 1
    for (int sp = 0; sp < 60; sp += 2) {
        // s = sp (even, bf = bfA)
        STAGE8(sp + 3, 0)
        RD_AF(af1, sp, 1)
        MM(0, af0, bfA)
        STAGE8(sp + 3, 1)
        VM(8)
        boundary_barrier();
        RD_AF(af0, sp + 1, 0) RD_BF(bfB, sp + 1)
        MM(1, af1, bfA)
        // s = sp+1 (odd, bf = bfB)
        STAGE8(sp + 4, 0)
        RD_AF(af1, sp + 1, 1)
        MM(0, af0, bfB)
        STAGE8(sp + 4, 1)
        VM(8)
        boundary_barrier();
        RD_AF(af0, sp + 2, 0) RD_BF(bfA, sp + 2)
        MM(1, af1, bfB)
    }

    // s = 60 (even): stage final sub-tile 63
    STAGE8(63, 0)
    RD_AF(af1, 60, 1)
    MM(0, af0, bfA)
    STAGE8(63, 1)
    VM(8)            // outstanding {61,62,63}=12 -> drains 61
    boundary_barrier();
    RD_AF(af0, 61, 0) RD_BF(bfB, 61)
    MM(1, af1, bfA)
    // s = 61 (odd): no stage
    RD_AF(af1, 61, 1)
    MM(0, af0, bfB)
    VM(4)            // outstanding {62,63}=8 -> drains 62
    boundary_barrier();
    RD_AF(af0, 62, 0) RD_BF(bfA, 62)
    MM(1, af1, bfB)
    // s = 62 (even)
    RD_AF(af1, 62, 1)
    MM(0, af0, bfA)
    VM(0)            // drains 63
    boundary_barrier();
    RD_AF(af0, 63, 0) RD_BF(bfB, 63)
    MM(1, af1, bfA)
    // s = 63 (odd)
    RD_AF(af1, 63, 1)
    MM(0, af0, bfB)
    MM(1, af1, bfB)

    // epilogue: C write
#pragma unroll
    for (int i = 0; i < 8; ++i) {
        int row0 = m0 + wm * 128 + (i >> 2) * 64 + (i & 3) * 16 + quad * 4;
#pragma unroll
        for (int nf = 0; nf < 4; ++nf) {
            int col = n0 + wn * 64 + nf * 16 + l16;
#pragma unroll
            for (int r = 0; r < 4; ++r)
                store_c(C, (size_t)(row0 + r) * 2048 + col, acc[i][nf][r]);
        }
    }
}

__global__ __launch_bounds__(512, 2) void gemm8_qkvg(const short* __restrict__ A,
    const short* __restrict__ B0, const short* __restrict__ B1,
    const short* __restrict__ B2, const short* __restrict__ B3,
    short* __restrict__ C0, short* __restrict__ C1,
    short* __restrict__ C2, short* __restrict__ C3) {
    extern __shared__ char smem[];
    const short* Bw; short* C;
    switch (blockIdx.z) {
        case 0:  Bw = B0; C = C0; break;
        case 1:  Bw = B1; C = C1; break;
        case 2:  Bw = B2; C = C2; break;
        default: Bw = B3; C = C3; break;
    }
    gemm8_tile<short>(A, Bw, C, smem);
}

__global__ __launch_bounds__(512, 2) void gemm8_out(const short* __restrict__ A,
    const short* __restrict__ Bw, float* __restrict__ C) {
    extern __shared__ char smem[];
    gemm8_tile<float>(A, Bw, C, smem);
}

// ---------------- a/b projection + decay/beta transform ----------------
// R7 rewrite. R6 failed (146us, VALUBusy 7.5%): c = lane&31 made every W-load a
// 32-row gather (32 transactions/instr), pure latency-bound. Constraint: coalescing
// needs >=16 consecutive lanes on the SAME W row. New: wave handles 2 rows; lanes
// split (grp = lane>>4, l16 = lane&15). Pass p: group grp computes col c = p*4+grp,
// its 16 lanes walk W[c] contiguously (coalesced 256B segments); x tiles held in
// registers across all 8 passes (read once); 4-level shfl_xor reduce inside the
// 16-lane group; lanes l16<2 write rows m0/m0+1. fp32 throughout (gating feeds a
// 2048-step multiplicative scan -- bf16 would drift).  ~180 VGPR, 2 blocks/CU.
__global__ __launch_bounds__(256) void ab_kernel(const float* __restrict__ x,
    const float* __restrict__ Wa, const float* __restrict__ Wb,
    const float* __restrict__ Alog, const float* __restrict__ dtb,
    float* __restrict__ gdec, float* __restrict__ beta) {
    int t = threadIdx.x;
    int wave = t >> 6, lane = t & 63;
    int l16 = lane & 15, grp = lane >> 4;
    int m0 = (blockIdx.x * 4 + wave) * 2;
    const float4* x0 = (const float4*)(x + (size_t)m0 * DIM);
    const float4* x1 = (const float4*)(x + (size_t)(m0 + 1) * DIM);

    float d0[8], d1[8];
#pragma unroll
    for (int p = 0; p < 8; ++p) { d0[p] = 0.f; d1[p] = 0.f; }

#pragma unroll
    for (int kt = 0; kt < 2; ++kt) {
        float4 xv0[16], xv1[16];
#pragma unroll
        for (int j = 0; j < 16; ++j) {
            xv0[j] = x0[kt * 256 + j * 16 + l16];
            xv1[j] = x1[kt * 256 + j * 16 + l16];
        }
#pragma unroll
        for (int p = 0; p < 8; ++p) {
            int c = p * 4 + grp;
            const float4* wr = (const float4*)((c < 16) ? (Wa + (size_t)c * DIM)
                                                        : (Wb + (size_t)(c - 16) * DIM));
            float s0 = 0.f, s1 = 0.f;
#pragma unroll
            for (int j = 0; j < 16; ++j) {
                float4 wv = wr[kt * 256 + j * 16 + l16];
                float4 a0 = xv0[j];
                float4 a1 = xv1[j];
                s0 += a0.x * wv.x + a0.y * wv.y + a0.z * wv.z + a0.w * wv.w;
                s1 += a1.x * wv.x + a1.y * wv.y + a1.z * wv.z + a1.w * wv.w;
            }
            d0[p] += s0;
            d1[p] += s1;
        }
    }

#pragma unroll
    for (int p = 0; p < 8; ++p) {
        float s0 = d0[p], s1 = d1[p];
#pragma unroll
        for (int off = 1; off < 16; off <<= 1) {
            s0 += __shfl_xor(s0, off);
            s1 += __shfl_xor(s1, off);
        }
        if (l16 < 2) {
            int c = p * 4 + grp;
            int m = m0 + l16;
            float sv = l16 ? s1 : s0;
            if (c < 16) {
                float sp = sv + dtb[c];
                float softp = (sp > 20.f) ? sp : log1pf(expf(sp));
                gdec[(size_t)m * NH + c] = expf(-expf(Alog[c]) * softp);
            } else {
                beta[(size_t)m * NH + (c - 16)] = 1.f / (1.f + expf(-sv));
            }
        }
    }
}

// ---------------- causal conv (K=4) + SiLU + l2norm(q,k)  (bf16 in/out) ----------------
__global__ __launch_bounds__(256) void conv_kernel(
    const short* __restrict__ qr, const short* __restrict__ kr, const short* __restrict__ vr,
    const float* __restrict__ cwq, const float* __restrict__ cbq,
    const float* __restrict__ cwk, const float* __restrict__ cbk,
    const float* __restrict__ cwv, const float* __restrict__ cbv,
    short* __restrict__ qn, short* __restrict__ kn, short* __restrict__ vc) {
    int gw   = blockIdx.x * 4 + (threadIdx.x >> 6);
    int lane = threadIdx.x & 63;
    int h  = gw & (NH - 1);
    int m  = gw >> 4;
    int tt = m & (S_LEN - 1);
    int c  = h * 128 + lane * 2;
    size_t rowbase = (size_t)m * KD + c;

    float4 wq0 = ((const float4*)cwq)[c], wq1 = ((const float4*)cwq)[c + 1];
    float4 wk0 = ((const float4*)cwk)[c], wk1 = ((const float4*)cwk)[c + 1];
    float4 wv0 = ((const float4*)cwv)[c], wv1 = ((const float4*)cwv)[c + 1];
    float q0 = cbq[c], q1 = cbq[c + 1];
    float k0 = cbk[c], k1 = cbk[c + 1];
    float v0 = cbv[c], v1 = cbv[c + 1];
    const float* wq0a = (const float*)&wq0; const float* wq1a = (const float*)&wq1;
    const float* wk0a = (const float*)&wk0; const float* wk1a = (const float*)&wk1;
    const float* wv0a = (const float*)&wv0; const float* wv1a = (const float*)&wv1;
#pragma unroll
    for (int j = 0; j < 4; ++j) {
        int ts = tt - 3 + j;
        if (ts >= 0) {
            long long rb = (long long)rowbase + (long long)(j - 3) * KD;
            unsigned uq = *(const unsigned*)(qr + rb);
            unsigned uk = *(const unsigned*)(kr + rb);
            unsigned uv = *(const unsigned*)(vr + rb);
            q0 += bf2f((short)(uq & 0xffff)) * wq0a[j]; q1 += bf2f((short)(uq >> 16)) * wq1a[j];
            k0 += bf2f((short)(uk & 0xffff)) * wk0a[j]; k1 += bf2f((short)(uk >> 16)) * wk1a[j];
            v0 += bf2f((short)(uv & 0xffff)) * wv0a[j]; v1 += bf2f((short)(uv >> 16)) * wv1a[j];
        }
    }
    q0 = silu_f(q0); q1 = silu_f(q1);
    k0 = silu_f(k0); k1 = silu_f(k1);
    v0 = silu_f(v0); v1 = silu_f(v1);

    float sq = q0 * q0 + q1 * q1;
    float sk = k0 * k0 + k1 * k1;
#pragma unroll
    for (int off = 1; off < 64; off <<= 1) {
        sq += __shfl_xor(sq, off);
        sk += __shfl_xor(sk, off);
    }
    float iq = 1.f / fmaxf(sqrtf(sq), 1e-12f);
    float ik = 1.f / fmaxf(sqrtf(sk), 1e-12f);
    unsigned oq = (unsigned)(unsigned short)f2bf(q0 * iq) | ((unsigned)(unsigned short)f2bf(q1 * iq) << 16);
    unsigned ok = (unsigned)(unsigned short)f2bf(k0 * ik) | ((unsigned)(unsigned short)f2bf(k1 * ik) << 16);
    unsigned ov = (unsigned)(unsigned short)f2bf(v0)      | ((unsigned)(unsigned short)f2bf(v1)      << 16);
    *(unsigned*)(qn + rowbase) = oq;
    *(unsigned*)(kn + rowbase) = ok;
    *(unsigned*)(vc + rowbase) = ov;
}

// ---------------- chunked delta-rule: per-chunk solve  ----------------
// NOTE: Tk and UvT global stores are chunk-XOR-swizzled (ch ^= row&7 on 16B chunks)
// so seq_kernel can global_load_lds them linearly and ds_read conflict-free.
__global__ __launch_bounds__(256) void solve_kernel(
    const short* __restrict__ kn, const short* __restrict__ vn,
    const float* __restrict__ gdec, const float* __restrict__ beta,
    short* __restrict__ UvT, short* __restrict__ Tk) {
    __shared__ short Pn[64][72];
    __shared__ short Pt[64][72];
    __shared__ short UT[128][72];
    __shared__ float Ls[64];
    __shared__ float Bs[64];

    int wg   = blockIdx.x;
    int half = wg & 1;
    int c    = (wg >> 1) & 31;
    int bh   = wg >> 6;
    int b = bh >> 4, h = bh & 15;
    int tid = threadIdx.x;
    int wave = tid >> 6, lane = tid & 63;
    int quad = lane >> 4, l16 = lane & 15;

    const short* Kb = kn + ((size_t)(b * S_LEN + c * CT)) * KD + h * 128;
    const short* Vb = vn + ((size_t)(b * S_LEN + c * CT)) * KD + h * 128;

    if (wave == 0) {
        float lg = __logf(gdec[((size_t)(b * S_LEN + c * CT) + lane) * NH + h]);
#pragma unroll
        for (int off = 1; off < 64; off <<= 1) {
            float y = __shfl_up(lg, off);
            if (lane >= off) lg += y;
        }
        Ls[lane] = lg;
        Bs[lane] = beta[((size_t)(b * S_LEN + c * CT) + lane) * NH + h];
    }
    __syncthreads();

    // build P = -A
    {
        floatx4 acc[4];
#pragma unroll
        for (int i = 0; i < 4; ++i) acc[i] = (floatx4){0.f, 0.f, 0.f, 0.f};
        for (int ks = 0; ks < 4; ++ks) {
            short8 af = *(const short8*)(Kb + (size_t)(wave * 16 + l16) * KD + ks * 32 + quad * 8);
#pragma unroll
            for (int it = 0; it < 4; ++it) {
                short8 bf = *(const short8*)(Kb + (size_t)(it * 16 + l16) * KD + ks * 32 + quad * 8);
                acc[it] = MFMA(af, bf, acc[it]);
            }
        }
#pragma unroll
        for (int it = 0; it < 4; ++it) {
            int icol = it * 16 + l16;
#pragma unroll
            for (int r = 0; r < 4; ++r) {
                int trow = wave * 16 + quad * 4 + r;
                float v = 0.f;
                if (icol < trow) v = -Bs[trow] * __expf(Ls[trow] - Ls[icol]) * acc[it][r];
                short bv = f2bf(v);
                Pn[trow][icol] = bv;
                Pt[icol][trow] = bv;
            }
        }
    }

    // RHS -> UT (transposed [n][t])
    {
        const short* src = half ? Kb : Vb;
        int tr = tid >> 2, seg = (tid & 3) * 32;
        float s = Bs[tr] * (half ? __expf(Ls[tr]) : 1.f);
#pragma unroll
        for (int j = 0; j < 4; ++j) {
            short8 d = *(const short8*)(src + (size_t)tr * KD + seg + j * 8);
#pragma unroll
            for (int e = 0; e < 8; ++e)
                UT[seg + j * 8 + e][tr] = f2bf(bf2f(d[e]) * s);
        }
    }
    __syncthreads();

    // 6 applications U <- U + P U, squaring P between
    for (int iter = 0; iter < 6; ++iter) {
        floatx4 acc[8];
#pragma unroll
        for (int nt = 0; nt < 8; ++nt) {
            short4v u4 = *(const short4v*)&UT[nt * 16 + l16][wave * 16 + quad * 4];
            floatx4 a;
#pragma unroll
            for (int e = 0; e < 4; ++e) a[e] = bf2f(u4[e]);
            acc[nt] = a;
        }
        for (int ks = 0; ks < 2; ++ks) {
            short8 af = *(const short8*)&Pn[wave * 16 + l16][ks * 32 + quad * 8];
#pragma unroll
            for (int nt = 0; nt < 8; ++nt) {
                short8 bf = *(const short8*)&UT[nt * 16 + l16][ks * 32 + quad * 8];
                acc[nt] = MFMA(af, bf, acc[nt]);
            }
        }
        __syncthreads();
        if (iter < 5) {
#pragma unroll
            for (int nt = 0; nt < 8; ++nt) {
                short4v w4;
#pragma unroll
                for (int e = 0; e < 4; ++e) w4[e] = f2bf(acc[nt][e]);
                *(short4v*)&UT[nt * 16 + l16][wave * 16 + quad * 4] = w4;
            }
            floatx4 pacc[4];
#pragma unroll
            for (int it = 0; it < 4; ++it) pacc[it] = (floatx4){0.f, 0.f, 0.f, 0.f};
            for (int ks = 0; ks < 2; ++ks) {
                short8 paf = *(const short8*)&Pn[wave * 16 + l16][ks * 32 + quad * 8];
#pragma unroll
                for (int it = 0; it < 4; ++it) {
                    short8 pbf = *(const short8*)&Pt[it * 16 + l16][ks * 32 + quad * 8];
                    pacc[it] = MFMA(paf, pbf, pacc[it]);
                }
            }
            __syncthreads();
#pragma unroll
            for (int it = 0; it < 4; ++it) {
                int icol = it * 16 + l16;
#pragma unroll
                for (int r = 0; r < 4; ++r) {
                    int trow = wave * 16 + quad * 4 + r;
                    short bv = f2bf(pacc[it][r]);
                    Pn[trow][icol] = bv;
                    Pt[icol][trow] = bv;
                }
            }
            __syncthreads();
        } else {
            size_t cb = (size_t)(bh * NC + c);
            if (half == 0) {
                // UvT swizzled store: row = nt*16+l16 (row&7 = l16&7)
                int usw = (((wave * 2 + (quad >> 1)) ^ (l16 & 7)) << 3) + ((quad & 1) << 2);
#pragma unroll
                for (int nt = 0; nt < 8; ++nt) {
                    short4v w4;
#pragma unroll
                    for (int e = 0; e < 4; ++e) w4[e] = f2bf(acc[nt][e]);
                    *(short4v*)(UvT + (cb * 128 + nt * 16 + l16) * 64 + usw) = w4;
                }
            } else {
#pragma unroll
                for (int nt = 0; nt < 8; ++nt)
#pragma unroll
                    for (int r = 0; r < 4; ++r) {
                        int trow = wave * 16 + quad * 4 + r;
                        int colsw = (((nt * 2 + (l16 >> 3)) ^ (trow & 7)) << 3) + (l16 & 7);
                        Tk[(cb * 64 + trow) * 128 + colsw] = f2bf(acc[nt][r]);
                    }
            }
        }
    }
}

// ---------------- chunk prep B: W, Qg, KtilT, gam63 ----------------
// Wb_/Qg/KtT stores chunk-XOR-swizzled (ch ^= row&7) to match seq_kernel's LDS reads.
__global__ __launch_bounds__(256) void prepb_kernel(
    const short* __restrict__ qn, const short* __restrict__ kn,
    const float* __restrict__ gdec,
    short* __restrict__ Wb_, short* __restrict__ Qg,
    short* __restrict__ KtT, float* __restrict__ gam63) {
    __shared__ short KT[128][72];
    __shared__ float Ls[64];
    int wg = blockIdx.x;
    int c = wg & 31, bh = wg >> 5;
    int b = bh >> 4, h = bh & 15;
    int tid = threadIdx.x, wave = tid >> 6, lane = tid & 63;
    int quad = lane >> 4, l16 = lane & 15;
    const short* Qb = qn + ((size_t)(b * S_LEN + c * CT)) * KD + h * 128;
    const short* Kb = kn + ((size_t)(b * S_LEN + c * CT)) * KD + h * 128;

    if (wave == 0) {
        float lg = __logf(gdec[((size_t)(b * S_LEN + c * CT) + lane) * NH + h]);
#pragma unroll
        for (int off = 1; off < 64; off <<= 1) {
            float y = __shfl_up(lg, off);
            if (lane >= off) lg += y;
        }
        Ls[lane] = lg;
    }
    __syncthreads();
    size_t cb = (size_t)(bh * NC + c);
    if (tid == 0) gam63[cb] = __expf(Ls[63]);

    // W = mask_{i<=t} e^{L_t-L_i} (q_t.k_i)
    {
        floatx4 acc[4];
#pragma unroll
        for (int i = 0; i < 4; ++i) acc[i] = (floatx4){0.f, 0.f, 0.f, 0.f};
        for (int ks = 0; ks < 4; ++ks) {
            short8 af = *(const short8*)(Qb + (size_t)(wave * 16 + l16) * KD + ks * 32 + quad * 8);
#pragma unroll
            for (int it = 0; it < 4; ++it) {
                short8 bf = *(const short8*)(Kb + (size_t)(it * 16 + l16) * KD + ks * 32 + quad * 8);
                acc[it] = MFMA(af, bf, acc[it]);
            }
        }
#pragma unroll
        for (int it = 0; it < 4; ++it) {
            int icol = it * 16 + l16;
#pragma unroll
            for (int r = 0; r < 4; ++r) {
                int trow = wave * 16 + quad * 4 + r;
                float v = (icol <= trow) ? __expf(Ls[trow] - Ls[icol]) * acc[it][r] : 0.f;
                int colsw = (((it * 2 + (l16 >> 3)) ^ (trow & 7)) << 3) + (l16 & 7);
                Wb_[(cb * 64 + trow) * 64 + colsw] = f2bf(v);
            }
        }
    }

    // Qg rows (e^{L_t} q_t)  +  stage scaled-K transpose
    {
        int tr = tid >> 2, seg = (tid & 3) * 32;
        float sq = __expf(Ls[tr]);
        float sk = __expf(Ls[63] - Ls[tr]);
#pragma unroll
        for (int j = 0; j < 4; ++j) {
            short8 dq = *(const short8*)(Qb + (size_t)tr * KD + seg + j * 8);
            short8 dk = *(const short8*)(Kb + (size_t)tr * KD + seg + j * 8);
            short8 oq;
#pragma unroll
            for (int e = 0; e < 8; ++e) {
                oq[e] = f2bf(bf2f(dq[e]) * sq);
                KT[seg + j * 8 + e][tr] = f2bf(bf2f(dk[e]) * sk);
            }
            int ch = (tid & 3) * 4 + j;
            *(short8*)(Qg + (cb * 64 + tr) * 128 + ((ch ^ (tr & 7)) << 3)) = oq;
        }
    }
    __syncthreads();
    {
        int dk = tid >> 1, seg = (tid & 1) * 32;
#pragma unroll
        for (int j = 0; j < 4; ++j) {
            short8 v = *(const short8*)&KT[dk][seg + j * 8];
            int ch = (tid & 1) * 4 + j;
            *(short8*)(KtT + (cb * 128 + dk) * 64 + ((ch ^ (dk & 7)) << 3)) = v;
        }
    }
}

// ---------------- sequential chunk pass: LDS double-buffered staging ----------------
// (R4: global_load_lds staging + counted vmcnt(16); verified, seq dropped out of top-5)
__global__ __launch_bounds__(256, 1) void seq_kernel(
    const short* __restrict__ UvT, const short* __restrict__ Tk,
    const short* __restrict__ Wb_, const short* __restrict__ Qg,
    const short* __restrict__ KtT, const float* __restrict__ gam63,
    short* __restrict__ ob) {
    extern __shared__ char smem[];
    const int BUF = 65536;
    const int TKO = 0, QGO = 16384, KTO = 32768, UVO = 49152, WO = 57344;
    short (*ST)[136] = (short (*)[136])(smem + 131072);
    short (*UTs)[72] = (short (*)[72])(smem + 131072 + 17408);

    int wg = blockIdx.x;
    int vh = wg & 1, bh = wg >> 1;
    int b = bh >> 4, h = bh & 15;
    int tid = threadIdx.x, wave = tid >> 6, lane = tid & 63;
    int quad = lane >> 4, l16 = lane & 15;
    int swk = l16 & 7;

    for (int i = tid; i < 64 * 136; i += 256) ((short*)(smem + 131072))[i] = 0;
    floatx4 sacc[8];
#pragma unroll
    for (int i = 0; i < 8; ++i) sacc[i] = (floatx4){0.f, 0.f, 0.f, 0.f};

    size_t cb0 = (size_t)bh * NC;
    int row16 = wave * 16 + l16;
    int chq[4];
#pragma unroll
    for (int ks = 0; ks < 4; ++ks) chq[ks] = (((ks * 4 + quad) ^ swk) << 4);
    int uvoff = (((wave * 2 + (quad >> 1)) ^ swk) << 4) + ((quad & 1) << 3);

#define STAGE_CHUNK(bsel_, c_)                                                       \
    {                                                                                \
        char* dst = smem + (bsel_) * BUF;                                            \
        size_t cbs = cb0 + (c_);                                                     \
        const char* gt = (const char*)Tk  + cbs * 16384 + wave * 1024 + lane * 16;   \
        const char* gq = (const char*)Qg  + cbs * 16384 + wave * 1024 + lane * 16;   \
        const char* gk = (const char*)KtT + cbs * 16384 + wave * 1024 + lane * 16;   \
        const char* gu = (const char*)UvT + cbs * 16384 + (size_t)vh * 8192 + wave * 1024 + lane * 16; \
        const char* gw = (const char*)Wb_ + cbs * 8192  + wave * 1024 + lane * 16;   \
        _Pragma("unroll")                                                            \
        for (int it = 0; it < 4; ++it) {                                             \
            load_lds16(gt + it * 4096, dst + TKO + it * 4096 + wave * 1024);         \
            load_lds16(gq + it * 4096, dst + QGO + it * 4096 + wave * 1024);         \
            load_lds16(gk + it * 4096, dst + KTO + it * 4096 + wave * 1024);         \
        }                                                                            \
        _Pragma("unroll")                                                            \
        for (int it = 0; it < 2; ++it) {                                             \
            load_lds16(gu + it * 4096, dst + UVO + it * 4096 + wave * 1024);         \
            load_lds16(gw + it * 4096, dst + WO  + it * 4096 + wave * 1024);         \
        }                                                                            \
    }

    STAGE_CHUNK(0, 0)
    float gamA = gam63[cb0];
    __syncthreads();   // drains stage(0) + ST zero-init, once

#pragma unroll 1
    for (int c = 0; c < NC; ++c) {
        float gamN = 0.f;
        if (c + 1 < NC) {
            gamN = gam63[cb0 + c + 1];
            STAGE_CHUNK((c + 1) & 1, c + 1)
        }
        const char* bufc = smem + (c & 1) * BUF;

        floatx4 uacc[4], oacc[4];
#pragma unroll
        for (int vt = 0; vt < 4; ++vt) {
            short4v u4 = *(const short4v*)(bufc + UVO + (vt * 16 + l16) * 128 + uvoff);
            floatx4 a;
#pragma unroll
            for (int e = 0; e < 4; ++e) a[e] = bf2f(u4[e]);
            uacc[vt] = a;
            oacc[vt] = (floatx4){0.f, 0.f, 0.f, 0.f};
        }
#pragma unroll
        for (int ks = 0; ks < 4; ++ks) {
            short8 tkf = *(const short8*)(bufc + TKO + row16 * 256 + chq[ks]);
            short8 qgf = *(const short8*)(bufc + QGO + row16 * 256 + chq[ks]);
            short8 afT = neg8(tkf);
#pragma unroll
            for (int vt = 0; vt < 4; ++vt) {
                short8 bf = *(const short8*)&ST[vt * 16 + l16][ks * 32 + quad * 8];
                uacc[vt] = MFMA(afT, bf, uacc[vt]);
                oacc[vt] = MFMA(qgf, bf, oacc[vt]);
            }
        }
#pragma unroll
        for (int vt = 0; vt < 4; ++vt) {
            short4v w4;
#pragma unroll
            for (int e = 0; e < 4; ++e) w4[e] = f2bf(uacc[vt][e]);
            *(short4v*)&UTs[vt * 16 + l16][wave * 16 + quad * 4] = w4;
        }
        lds_barrier();
#pragma unroll
        for (int ks = 0; ks < 2; ++ks) {
            short8 wf = *(const short8*)(bufc + WO + row16 * 128 + chq[ks]);
#pragma unroll
            for (int vt = 0; vt < 4; ++vt) {
                short8 bf = *(const short8*)&UTs[vt * 16 + l16][ks * 32 + quad * 8];
                oacc[vt] = MFMA(wf, bf, oacc[vt]);
            }
        }
#pragma unroll
        for (int vt = 0; vt < 4; ++vt)
#pragma unroll
            for (int r = 0; r < 4; ++r) {
                int m = b * S_LEN + c * CT + wave * 16 + quad * 4 + r;
                ob[(size_t)m * VD + h * 128 + vh * 64 + vt * 16 + l16] = f2bf(oacc[vt][r]);
            }
#pragma unroll
        for (int dt = 0; dt < 8; ++dt)
#pragma unroll
            for (int e = 0; e < 4; ++e) sacc[dt][e] *= gamA;
#pragma unroll
        for (int ks = 0; ks < 2; ++ks) {
            short8 af = *(const short8*)&UTs[wave * 16 + l16][ks * 32 + quad * 8];
#pragma unroll
            for (int dt = 0; dt < 8; ++dt) {
                short8 ktf = *(const short8*)(bufc + KTO + (dt * 16 + l16) * 128 + chq[ks]);
                sacc[dt] = MFMA(af, ktf, sacc[dt]);
            }
        }
#pragma unroll
        for (int dt = 0; dt < 8; ++dt)
#pragma unroll
            for (int r = 0; r < 4; ++r)
                ST[wave * 16 + quad * 4 + r][dt * 16 + l16] = f2bf(sacc[dt][r]);

        if (c + 1 < NC) {
            asm volatile("s_waitcnt lgkmcnt(0)" ::: "memory");
            VM(16)      // stage(c+1) drained; ob stores (16 newest) stay in flight
            __builtin_amdgcn_s_barrier();
        }
        gamA = gamN;
    }
#undef STAGE_CHUNK
}

// ---------------- RMSNorm + SiLU gate (bf16 in/out) ----------------
__global__ __launch_bounds__(256) void rms_gate_kernel(
    const short* __restrict__ o, const short* __restrict__ graw,
    const float* __restrict__ nw, short* __restrict__ og) {
    __shared__ float red[4];
    int m = blockIdx.x, t = threadIdx.x;
    short8 a = ((const short8*)(o + (size_t)m * VD))[t];
    float av[8];
#pragma unroll
    for (int i = 0; i < 8; ++i) av[i] = bf2f(a[i]);
    float ss = 0.f;
#pragma unroll
    for (int i = 0; i < 8; ++i) ss += av[i] * av[i];
#pragma unroll
    for (int off = 1; off < 64; off <<= 1) ss += __shfl_xor(ss, off);
    if ((t & 63) == 0) red[t >> 6] = ss;
    __syncthreads();
    float tot = red[0] + red[1] + red[2] + red[3];
    float sc = rsqrtf(tot * (1.f / VD) + 1e-6f);
    short8 gv = ((const short8*)(graw + (size_t)m * VD))[t];
    float4 n0 = ((const float4*)nw)[2 * t];
    float4 n1 = ((const float4*)nw)[2 * t + 1];
    const float* na = (const float*)&n0;
    const float* nb = (const float*)&n1;
    short8 ov;
#pragma unroll
    for (int i = 0; i < 4; ++i) ov[i]     = f2bf(av[i]     * sc * na[i] * silu_f(bf2f(gv[i])));
#pragma unroll
    for (int i = 0; i < 4; ++i) ov[i + 4] = f2bf(av[i + 4] * sc * nb[i] * silu_f(bf2f(gv[i + 4])));
    ((short8*)(og + (size_t)m * VD))[t] = ov;
}

// ---------------- host launcher ----------------
extern "C" void kernel_launch(void* const* d_in, const int* in_sizes, int n_in,
                              void* d_out, int out_size, void* d_ws, size_t ws_size,
                              hipStream_t stream) {
    const float* x    = (const float*)d_in[0];
    const float* Wq   = (const float*)d_in[1];
    const float* Wk   = (const float*)d_in[2];
    const float* Wv   = (const float*)d_in[3];
    const float* Wa   = (const float*)d_in[4];
    const float* Wb   = (const float*)d_in[5];
    const float* Wg   = (const float*)d_in[6];
    const float* Wo   = (const float*)d_in[7];
    const float* cwq  = (const float*)d_in[8];
    const float* cbq  = (const float*)d_in[9];
    const float* cwk  = (const float*)d_in[10];
    const float* cbk  = (const float*)d_in[11];
    const float* cwv  = (const float*)d_in[12];
    const float* cbv  = (const float*)d_in[13];
    const float* Alog = (const float*)d_in[14];
    const float* dtb  = (const float*)d_in[15];
    const float* nw   = (const float*)d_in[16];

    char* ws = (char*)d_ws;
    short* Wob = (short*)(ws);
    short* xb  = (short*)(ws + 8 * MB);
    short* Wqb = (short*)(ws + 24 * MB);
    short* Wkb = (short*)(ws + 32 * MB);
    short* Wvb = (short*)(ws + 40 * MB);
    short* Wgb = (short*)(ws + 48 * MB);
    short* qrb = (short*)(ws + 56 * MB);
    short* krb = (short*)(ws + 72 * MB);
    short* vrb = (short*)(ws + 88 * MB);
    short* grb = (short*)(ws + 104 * MB);
    short* qnb = (short*)(ws + 8 * MB);
    short* knb = (short*)(ws + 24 * MB);
    short* vnb = (short*)(ws + 40 * MB);
    float* gdec = (float*)(ws + 120 * MB);
    float* beta = (float*)(ws + 120 * MB + 262144);
    short* ob  = qrb;   // reuse
    short* ogb = krb;   // reuse
    // chunked-scan buffers
    short* UvT  = (short*)(ws + 121 * MB);   // [1024][128][64]
    short* Tkb  = (short*)(ws + 137 * MB);   // [1024][64][128]
    short* Wbuf = (short*)(ws + 153 * MB);   // [1024][64][64]
    short* Qgb  = (short*)(ws + 161 * MB);   // [1024][64][128]
    short* KtT  = (short*)(ws + 177 * MB);   // [1024][128][64]
    float* gm63 = (float*)(ws + 193 * MB);   // [1024]

    // one-time: allow large dynamic LDS
    static bool attr_done = false;
    if (!attr_done) {
        hipFuncSetAttribute((const void*)gemm8_qkvg,
                            hipFuncAttributeMaxDynamicSharedMemorySize, 131072);
        hipFuncSetAttribute((const void*)gemm8_out,
                            hipFuncAttributeMaxDynamicSharedMemorySize, 131072);
        hipFuncSetAttribute((const void*)seq_kernel,
                            hipFuncAttributeMaxDynamicSharedMemorySize, 157696);
        attr_done = true;
    }

    // 1. fp32 -> bf16 conversions (single launch)
    cvt_all_kernel<<<dim3(4096, 6), 256, 0, stream>>>(x, Wq, Wk, Wv, Wg, Wo,
                                                      xb, Wqb, Wkb, Wvb, Wgb, Wob);

    // 2. a/b projection + decay/beta (coalesced 16-lane-group GEMV)
    ab_kernel<<<512, 256, 0, stream>>>(x, Wa, Wb, Alog, dtb, gdec, beta);

    // 3. fused q/k/v/gate projections (256^2 frag-prefetch pipeline, 128 KiB LDS)
    gemm8_qkvg<<<dim3(128, 1, 4), 512, 131072, stream>>>(xb, Wqb, Wkb, Wvb, Wgb,
                                                         qrb, krb, vrb, grb);

    // 4. causal conv + SiLU + l2norm
    conv_kernel<<<16384, 256, 0, stream>>>(qrb, krb, vrb,
                                           cwq, cbq, cwk, cbk, cwv, cbv, qnb, knb, vnb);

    // 5. chunked delta-rule
    solve_kernel<<<2048, 256, 0, stream>>>(knb, vnb, gdec, beta, UvT, Tkb);
    prepb_kernel<<<1024, 256, 0, stream>>>(qnb, knb, gdec, Wbuf, Qgb, KtT, gm63);
    seq_kernel<<<64, 256, 157696, stream>>>(UvT, Tkb, Wbuf, Qgb, KtT, gm63, ob);

    // 6. RMSNorm + SiLU gate
    rms_gate_kernel<<<4096, 256, 0, stream>>>(ob, grb, nw, ogb);

    // 7. output projection (256^2 frag-prefetch pipeline, fp32 out)
    gemm8_out<<<dim3(128, 1, 1), 512, 131072, stream>>>(ogb, Wob, (float*)d_out);
}

// Round 8
// 663.818 us; speedup vs baseline: 1.6480x; 1.6480x over previous
//
#include <hip/hip_runtime.h>

// ---------------- problem constants ----------------
#define S_LEN   2048
#define NH      16
#define DIM     2048
#define KD      2048
#define VD      2048
#define MB      1048576ull
#define CT      64     // chunk length
#define NC      32     // chunks per sequence

typedef short  short8  __attribute__((ext_vector_type(8)));
typedef short  short4v __attribute__((ext_vector_type(4)));
typedef float  floatx4 __attribute__((ext_vector_type(4)));

#define MFMA(a, b, c) __builtin_amdgcn_mfma_f32_16x16x32_bf16((a), (b), (c), 0, 0, 0)

// fp32 -> bf16, round-to-nearest-even
__device__ inline short f2bf(float x) {
    unsigned u = __float_as_uint(x);
    unsigned r = (u + 0x7fffu + ((u >> 16) & 1u)) >> 16;
    return (short)r;
}
__device__ inline float bf2f(short s) {
    return __uint_as_float(((unsigned)(unsigned short)s) << 16);
}
__device__ inline float silu_f(float x) { return x / (1.f + __expf(-x)); }

__device__ inline short8 neg8(short8 a) {
    unsigned* p = (unsigned*)&a;
    p[0] ^= 0x80008000u; p[1] ^= 0x80008000u;
    p[2] ^= 0x80008000u; p[3] ^= 0x80008000u;
    return a;
}

// async global->LDS, 16B per lane; LDS dest is wave-uniform base (+lane*16 implicit)
__device__ inline void load_lds16(const void* g, void* l) {
    __builtin_amdgcn_global_load_lds(
        (const __attribute__((address_space(1))) unsigned int*)g,
        (__attribute__((address_space(3))) unsigned int*)l, 16, 0, 0);
}

__device__ inline void store_c(float* C, size_t idx, float v) { C[idx] = v; }
__device__ inline void store_c(short* C, size_t idx, float v) { C[idx] = f2bf(v); }

// LDS-only barrier (no vmcnt drain)
__device__ __forceinline__ void lds_barrier() {
    asm volatile("s_waitcnt lgkmcnt(0)" ::: "memory");
    __builtin_amdgcn_s_barrier();
}

// Boundary barrier for the GEMM pipeline: lgkmcnt(0) before s_barrier guarantees every
// wave's issued ds_reads of the retiring buffer completed before any wave can DMA over
// it (cross-wave WAR).  Memory-clobber asm on both sides pins LDS ops against motion
// across the barrier.
__device__ __forceinline__ void boundary_barrier() {
    asm volatile("s_waitcnt lgkmcnt(0)" ::: "memory");
    __builtin_amdgcn_s_barrier();
    asm volatile("" ::: "memory");
}

#define VM(n_) asm volatile("s_waitcnt vmcnt(" #n_ ")" ::: "memory");

// ---------------- fp32 -> bf16 conversion (all 6 tensors, one launch) ----------------
__global__ __launch_bounds__(256) void cvt_all_kernel(
    const float* __restrict__ x,  const float* __restrict__ Wq,
    const float* __restrict__ Wk, const float* __restrict__ Wv,
    const float* __restrict__ Wg, const float* __restrict__ Wo,
    short* __restrict__ xb,  short* __restrict__ Wqb, short* __restrict__ Wkb,
    short* __restrict__ Wvb, short* __restrict__ Wgb, short* __restrict__ Wob) {
    const float* in; short* out; int n8;
    switch (blockIdx.y) {
        case 0:  in = x;  out = xb;  n8 = 1048576; break;
        case 1:  in = Wq; out = Wqb; n8 = 524288;  break;
        case 2:  in = Wk; out = Wkb; n8 = 524288;  break;
        case 3:  in = Wv; out = Wvb; n8 = 524288;  break;
        case 4:  in = Wg; out = Wgb; n8 = 524288;  break;
        default: in = Wo; out = Wob; n8 = 524288;  break;
    }
    int i = blockIdx.x * 256 + threadIdx.x;
    if (i >= n8) return;
    float4 a = ((const float4*)in)[2 * i];
    float4 b = ((const float4*)in)[2 * i + 1];
    short8 o;
    o[0] = f2bf(a.x); o[1] = f2bf(a.y); o[2] = f2bf(a.z); o[3] = f2bf(a.w);
    o[4] = f2bf(b.x); o[5] = f2bf(b.y); o[6] = f2bf(b.z); o[7] = f2bf(b.w);
    ((short8*)out)[i] = o;
}

// ---------------- 256^2 bf16 GEMM, register-fragment-prefetch pipeline ----------------
// (R5, verified: 1 barrier/sub-tile, frag prefetch 1 phase ahead, counted vmcnt(8);
//  swizzle chunk ^= (row>>1)&3, conflicts == 0 measured R4.)

#define STAGE8(s_, isB_)                                                     \
    {                                                                        \
        const char* gsrc = (isB_) ? (const char*)Bw : (const char*)A;        \
        int t0 = (isB_) ? n0 : m0;                                           \
        char* dbase = smem + ((s_) & 3) * 32768 + (isB_) * 16384;            \
        _Pragma("unroll")                                                    \
        for (int ld = 0; ld < 2; ++ld) {                                     \
            int ch = ld * 8 + wave;                                          \
            int Pl = (ch << 10) + (lane << 4);                               \
            int Q  = Pl ^ (((lane >> 3) & 3) << 4);                          \
            const char* src = gsrc + ((size_t)(t0 + (Q >> 6)) << 12)         \
                              + ((size_t)(s_) << 6) + (Q & 63);              \
            load_lds16(src, dbase + (ch << 10));                             \
        }                                                                    \
    }

#define RD_AF(dst_, s_, qm_)                                                 \
    {                                                                        \
        const char* sb_ = smem + ((s_) & 3) * 32768;                         \
        _Pragma("unroll")                                                    \
        for (int mf = 0; mf < 4; ++mf)                                       \
            dst_[mf] = *(const short8*)(sb_ +                                \
                ((rowA_base + (qm_) * 64 + mf * 16) << 6) + qsw);            \
    }

#define RD_BF(dst_, s_)                                                      \
    {                                                                        \
        const char* sb_ = smem + ((s_) & 3) * 32768 + 16384;                 \
        _Pragma("unroll")                                                    \
        for (int nf = 0; nf < 4; ++nf)                                       \
            dst_[nf] = *(const short8*)(sb_ +                                \
                ((rowB_base + nf * 16) << 6) + qsw);                         \
    }

#define MM(qm_, af_, bf_)                                                    \
    {                                                                        \
        __builtin_amdgcn_s_setprio(1);                                       \
        _Pragma("unroll")                                                    \
        for (int mf = 0; mf < 4; ++mf)                                       \
            _Pragma("unroll")                                                \
            for (int nf = 0; nf < 4; ++nf)                                   \
                acc[(qm_) * 4 + mf][nf] =                                    \
                    MFMA(af_[mf], bf_[nf], acc[(qm_) * 4 + mf][nf]);         \
        __builtin_amdgcn_s_setprio(0);                                       \
    }

template <typename OutT>
__device__ __forceinline__ void gemm8_tile(const short* __restrict__ A,
                                           const short* __restrict__ Bw,
                                           OutT* __restrict__ C, char* smem) {
    int x  = blockIdx.x;
    int xs = (x & 7) * 16 + (x >> 3);            // XCD-chunked swizzle (128 % 8 == 0)
    int m0 = (xs >> 3) * 256;                    // 16 m-tiles
    int n0 = (xs & 7) * 256;                     // 8 n-tiles
    int tid  = threadIdx.x;
    int wave = tid >> 6, lane = tid & 63;
    int l16  = lane & 15, quad = lane >> 4;
    int wm = wave >> 2, wn = wave & 3;
    int qsw = ((quad ^ ((l16 >> 1) & 3)) << 4);  // read-side swizzled 16B-chunk offset
    int rowA_base = wm * 128 + l16;
    int rowB_base = wn * 64 + l16;

    floatx4 acc[8][4];
#pragma unroll
    for (int i = 0; i < 8; ++i)
#pragma unroll
        for (int j = 0; j < 4; ++j) acc[i][j] = (floatx4){0.f, 0.f, 0.f, 0.f};
    short8 af0[4], af1[4], bfA[4], bfB[4];

    // prologue: stage sub-tiles 0,1,2; drain s0; publish; prefetch first fragments
    STAGE8(0, 0) STAGE8(0, 1)
    STAGE8(1, 0) STAGE8(1, 1)
    STAGE8(2, 0) STAGE8(2, 1)
    VM(8)
    boundary_barrier();
    RD_AF(af0, 0, 0) RD_BF(bfA, 0)

    // steady state: sub-tiles 0..59, unrolled x2 for bfA/bfB parity
#pragma unroll 1
    for (int sp = 0; sp < 60; sp += 2) {
        // s = sp (even, bf = bfA)
        STAGE8(sp + 3, 0)
        RD_AF(af1, sp, 1)
        MM(0, af0, bfA)
        STAGE8(sp + 3, 1)
        VM(8)
        boundary_barrier();
        RD_AF(af0, sp + 1, 0) RD_BF(bfB, sp + 1)
        MM(1, af1, bfA)
        // s = sp+1 (odd, bf = bfB)
        STAGE8(sp + 4, 0)
        RD_AF(af1, sp + 1, 1)
        MM(0, af0, bfB)
        STAGE8(sp + 4, 1)
        VM(8)
        boundary_barrier();
        RD_AF(af0, sp + 2, 0) RD_BF(bfA, sp + 2)
        MM(1, af1, bfB)
    }

    // s = 60 (even): stage final sub-tile 63
    STAGE8(63, 0)
    RD_AF(af1, 60, 1)
    MM(0, af0, bfA)
    STAGE8(63, 1)
    VM(8)            // outstanding {61,62,63}=12 -> drains 61
    boundary_barrier();
    RD_AF(af0, 61, 0) RD_BF(bfB, 61)
    MM(1, af1, bfA)
    // s = 61 (odd): no stage
    RD_AF(af1, 61, 1)
    MM(0, af0, bfB)
    VM(4)            // outstanding {62,63}=8 -> drains 62
    boundary_barrier();
    RD_AF(af0, 62, 0) RD_BF(bfA, 62)
    MM(1, af1, bfB)
    // s = 62 (even)
    RD_AF(af1, 62, 1)
    MM(0, af0, bfA)
    VM(0)            // drains 63
    boundary_barrier();
    RD_AF(af0, 63, 0) RD_BF(bfB, 63)
    MM(1, af1, bfA)
    // s = 63 (odd)
    RD_AF(af1, 63, 1)
    MM(0, af0, bfB)
    MM(1, af1, bfB)

    // epilogue: C write
#pragma unroll
    for (int i = 0; i < 8; ++i) {
        int row0 = m0 + wm * 128 + (i >> 2) * 64 + (i & 3) * 16 + quad * 4;
#pragma unroll
        for (int nf = 0; nf < 4; ++nf) {
            int col = n0 + wn * 64 + nf * 16 + l16;
#pragma unroll
            for (int r = 0; r < 4; ++r)
                store_c(C, (size_t)(row0 + r) * 2048 + col, acc[i][nf][r]);
        }
    }
}

__global__ __launch_bounds__(512, 2) void gemm8_qkvg(const short* __restrict__ A,
    const short* __restrict__ B0, const short* __restrict__ B1,
    const short* __restrict__ B2, const short* __restrict__ B3,
    short* __restrict__ C0, short* __restrict__ C1,
    short* __restrict__ C2, short* __restrict__ C3) {
    extern __shared__ char smem[];
    const short* Bw; short* C;
    switch (blockIdx.z) {
        case 0:  Bw = B0; C = C0; break;
        case 1:  Bw = B1; C = C1; break;
        case 2:  Bw = B2; C = C2; break;
        default: Bw = B3; C = C3; break;
    }
    gemm8_tile<short>(A, Bw, C, smem);
}

__global__ __launch_bounds__(512, 2) void gemm8_out(const short* __restrict__ A,
    const short* __restrict__ Bw, float* __restrict__ C) {
    extern __shared__ char smem[];
    gemm8_tile<float>(A, Bw, C, smem);
}

// ---------------- a/b projection + decay/beta transform ----------------
// R8. R7's register x-cache (32 float4/thread) hit the 256-VGPR cap and spilled to
// scratch (WRITE_SIZE 440MB, 475us). Keep R7's coalescing shape, drop the cache:
// wave handles 2 rows, lanes split (grp = lane>>4, l16 = lane&15); pass p: group grp
// computes col c = p*4+grp; 16 lanes walk W[c] AND x rows with identical coalesced
// float4 patterns. x rows (8KB) are L1-resident after pass 0, so the 8x re-read is
// L1-hit, not HBM. ~50 VGPR, no spill. fp32 throughout (gating feeds a 2048-step
// multiplicative scan).
__global__ __launch_bounds__(256) void ab_kernel(const float* __restrict__ x,
    const float* __restrict__ Wa, const float* __restrict__ Wb,
    const float* __restrict__ Alog, const float* __restrict__ dtb,
    float* __restrict__ gdec, float* __restrict__ beta) {
    int t = threadIdx.x;
    int wave = t >> 6, lane = t & 63;
    int l16 = lane & 15, grp = lane >> 4;
    int m0 = (blockIdx.x * 4 + wave) * 2;
    const float4* x0 = (const float4*)(x + (size_t)m0 * DIM);
    const float4* x1 = (const float4*)(x + (size_t)(m0 + 1) * DIM);

#pragma unroll 1
    for (int p = 0; p < 8; ++p) {
        int c = p * 4 + grp;
        const float4* wr = (const float4*)((c < 16) ? (Wa + (size_t)c * DIM)
                                                    : (Wb + (size_t)(c - 16) * DIM));
        float s0 = 0.f, s1 = 0.f;
#pragma unroll 8
        for (int j = 0; j < 32; ++j) {
            float4 wv = wr[j * 16 + l16];
            float4 a0 = x0[j * 16 + l16];
            float4 a1 = x1[j * 16 + l16];
            s0 += a0.x * wv.x + a0.y * wv.y + a0.z * wv.z + a0.w * wv.w;
            s1 += a1.x * wv.x + a1.y * wv.y + a1.z * wv.z + a1.w * wv.w;
        }
#pragma unroll
        for (int off = 1; off < 16; off <<= 1) {
            s0 += __shfl_xor(s0, off);
            s1 += __shfl_xor(s1, off);
        }
        if (l16 < 2) {
            int m = m0 + l16;
            float sv = l16 ? s1 : s0;
            if (c < 16) {
                float sp = sv + dtb[c];
                float softp = (sp > 20.f) ? sp : log1pf(expf(sp));
                gdec[(size_t)m * NH + c] = expf(-expf(Alog[c]) * softp);
            } else {
                beta[(size_t)m * NH + (c - 16)] = 1.f / (1.f + expf(-sv));
            }
        }
    }
}

// ---------------- causal conv (K=4) + SiLU + l2norm(q,k)  (bf16 in/out) ----------------
__global__ __launch_bounds__(256) void conv_kernel(
    const short* __restrict__ qr, const short* __restrict__ kr, const short* __restrict__ vr,
    const float* __restrict__ cwq, const float* __restrict__ cbq,
    const float* __restrict__ cwk, const float* __restrict__ cbk,
    const float* __restrict__ cwv, const float* __restrict__ cbv,
    short* __restrict__ qn, short* __restrict__ kn, short* __restrict__ vc) {
    int gw   = blockIdx.x * 4 + (threadIdx.x >> 6);
    int lane = threadIdx.x & 63;
    int h  = gw & (NH - 1);
    int m  = gw >> 4;
    int tt = m & (S_LEN - 1);
    int c  = h * 128 + lane * 2;
    size_t rowbase = (size_t)m * KD + c;

    float4 wq0 = ((const float4*)cwq)[c], wq1 = ((const float4*)cwq)[c + 1];
    float4 wk0 = ((const float4*)cwk)[c], wk1 = ((const float4*)cwk)[c + 1];
    float4 wv0 = ((const float4*)cwv)[c], wv1 = ((const float4*)cwv)[c + 1];
    float q0 = cbq[c], q1 = cbq[c + 1];
    float k0 = cbk[c], k1 = cbk[c + 1];
    float v0 = cbv[c], v1 = cbv[c + 1];
    const float* wq0a = (const float*)&wq0; const float* wq1a = (const float*)&wq1;
    const float* wk0a = (const float*)&wk0; const float* wk1a = (const float*)&wk1;
    const float* wv0a = (const float*)&wv0; const float* wv1a = (const float*)&wv1;
#pragma unroll
    for (int j = 0; j < 4; ++j) {
        int ts = tt - 3 + j;
        if (ts >= 0) {
            long long rb = (long long)rowbase + (long long)(j - 3) * KD;
            unsigned uq = *(const unsigned*)(qr + rb);
            unsigned uk = *(const unsigned*)(kr + rb);
            unsigned uv = *(const unsigned*)(vr + rb);
            q0 += bf2f((short)(uq & 0xffff)) * wq0a[j]; q1 += bf2f((short)(uq >> 16)) * wq1a[j];
            k0 += bf2f((short)(uk & 0xffff)) * wk0a[j]; k1 += bf2f((short)(uk >> 16)) * wk1a[j];
            v0 += bf2f((short)(uv & 0xffff)) * wv0a[j]; v1 += bf2f((short)(uv >> 16)) * wv1a[j];
        }
    }
    q0 = silu_f(q0); q1 = silu_f(q1);
    k0 = silu_f(k0); k1 = silu_f(k1);
    v0 = silu_f(v0); v1 = silu_f(v1);

    float sq = q0 * q0 + q1 * q1;
    float sk = k0 * k0 + k1 * k1;
#pragma unroll
    for (int off = 1; off < 64; off <<= 1) {
        sq += __shfl_xor(sq, off);
        sk += __shfl_xor(sk, off);
    }
    float iq = 1.f / fmaxf(sqrtf(sq), 1e-12f);
    float ik = 1.f / fmaxf(sqrtf(sk), 1e-12f);
    unsigned oq = (unsigned)(unsigned short)f2bf(q0 * iq) | ((unsigned)(unsigned short)f2bf(q1 * iq) << 16);
    unsigned ok = (unsigned)(unsigned short)f2bf(k0 * ik) | ((unsigned)(unsigned short)f2bf(k1 * ik) << 16);
    unsigned ov = (unsigned)(unsigned short)f2bf(v0)      | ((unsigned)(unsigned short)f2bf(v1)      << 16);
    *(unsigned*)(qn + rowbase) = oq;
    *(unsigned*)(kn + rowbase) = ok;
    *(unsigned*)(vc + rowbase) = ov;
}

// ---------------- chunked delta-rule: per-chunk solve  ----------------
// NOTE: Tk and UvT global stores are chunk-XOR-swizzled (ch ^= row&7 on 16B chunks)
// so seq_kernel can global_load_lds them linearly and ds_read conflict-free.
__global__ __launch_bounds__(256) void solve_kernel(
    const short* __restrict__ kn, const short* __restrict__ vn,
    const float* __restrict__ gdec, const float* __restrict__ beta,
    short* __restrict__ UvT, short* __restrict__ Tk) {
    __shared__ short Pn[64][72];
    __shared__ short Pt[64][72];
    __shared__ short UT[128][72];
    __shared__ float Ls[64];
    __shared__ float Bs[64];

    int wg   = blockIdx.x;
    int half = wg & 1;
    int c    = (wg >> 1) & 31;
    int bh   = wg >> 6;
    int b = bh >> 4, h = bh & 15;
    int tid = threadIdx.x;
    int wave = tid >> 6, lane = tid & 63;
    int quad = lane >> 4, l16 = lane & 15;

    const short* Kb = kn + ((size_t)(b * S_LEN + c * CT)) * KD + h * 128;
    const short* Vb = vn + ((size_t)(b * S_LEN + c * CT)) * KD + h * 128;

    if (wave == 0) {
        float lg = __logf(gdec[((size_t)(b * S_LEN + c * CT) + lane) * NH + h]);
#pragma unroll
        for (int off = 1; off < 64; off <<= 1) {
            float y = __shfl_up(lg, off);
            if (lane >= off) lg += y;
        }
        Ls[lane] = lg;
        Bs[lane] = beta[((size_t)(b * S_LEN + c * CT) + lane) * NH + h];
    }
    __syncthreads();

    // build P = -A
    {
        floatx4 acc[4];
#pragma unroll
        for (int i = 0; i < 4; ++i) acc[i] = (floatx4){0.f, 0.f, 0.f, 0.f};
        for (int ks = 0; ks < 4; ++ks) {
            short8 af = *(const short8*)(Kb + (size_t)(wave * 16 + l16) * KD + ks * 32 + quad * 8);
#pragma unroll
            for (int it = 0; it < 4; ++it) {
                short8 bf = *(const short8*)(Kb + (size_t)(it * 16 + l16) * KD + ks * 32 + quad * 8);
                acc[it] = MFMA(af, bf, acc[it]);
            }
        }
#pragma unroll
        for (int it = 0; it < 4; ++it) {
            int icol = it * 16 + l16;
#pragma unroll
            for (int r = 0; r < 4; ++r) {
                int trow = wave * 16 + quad * 4 + r;
                float v = 0.f;
                if (icol < trow) v = -Bs[trow] * __expf(Ls[trow] - Ls[icol]) * acc[it][r];
                short bv = f2bf(v);
                Pn[trow][icol] = bv;
                Pt[icol][trow] = bv;
            }
        }
    }

    // RHS -> UT (transposed [n][t])
    {
        const short* src = half ? Kb : Vb;
        int tr = tid >> 2, seg = (tid & 3) * 32;
        float s = Bs[tr] * (half ? __expf(Ls[tr]) : 1.f);
#pragma unroll
        for (int j = 0; j < 4; ++j) {
            short8 d = *(const short8*)(src + (size_t)tr * KD + seg + j * 8);
#pragma unroll
            for (int e = 0; e < 8; ++e)
                UT[seg + j * 8 + e][tr] = f2bf(bf2f(d[e]) * s);
        }
    }
    __syncthreads();

    // 6 applications U <- U + P U, squaring P between
    for (int iter = 0; iter < 6; ++iter) {
        floatx4 acc[8];
#pragma unroll
        for (int nt = 0; nt < 8; ++nt) {
            short4v u4 = *(const short4v*)&UT[nt * 16 + l16][wave * 16 + quad * 4];
            floatx4 a;
#pragma unroll
            for (int e = 0; e < 4; ++e) a[e] = bf2f(u4[e]);
            acc[nt] = a;
        }
        for (int ks = 0; ks < 2; ++ks) {
            short8 af = *(const short8*)&Pn[wave * 16 + l16][ks * 32 + quad * 8];
#pragma unroll
            for (int nt = 0; nt < 8; ++nt) {
                short8 bf = *(const short8*)&UT[nt * 16 + l16][ks * 32 + quad * 8];
                acc[nt] = MFMA(af, bf, acc[nt]);
            }
        }
        __syncthreads();
        if (iter < 5) {
#pragma unroll
            for (int nt = 0; nt < 8; ++nt) {
                short4v w4;
#pragma unroll
                for (int e = 0; e < 4; ++e) w4[e] = f2bf(acc[nt][e]);
                *(short4v*)&UT[nt * 16 + l16][wave * 16 + quad * 4] = w4;
            }
            floatx4 pacc[4];
#pragma unroll
            for (int it = 0; it < 4; ++it) pacc[it] = (floatx4){0.f, 0.f, 0.f, 0.f};
            for (int ks = 0; ks < 2; ++ks) {
                short8 paf = *(const short8*)&Pn[wave * 16 + l16][ks * 32 + quad * 8];
#pragma unroll
                for (int it = 0; it < 4; ++it) {
                    short8 pbf = *(const short8*)&Pt[it * 16 + l16][ks * 32 + quad * 8];
                    pacc[it] = MFMA(paf, pbf, pacc[it]);
                }
            }
            __syncthreads();
#pragma unroll
            for (int it = 0; it < 4; ++it) {
                int icol = it * 16 + l16;
#pragma unroll
                for (int r = 0; r < 4; ++r) {
                    int trow = wave * 16 + quad * 4 + r;
                    short bv = f2bf(pacc[it][r]);
                    Pn[trow][icol] = bv;
                    Pt[icol][trow] = bv;
                }
            }
            __syncthreads();
        } else {
            size_t cb = (size_t)(bh * NC + c);
            if (half == 0) {
                // UvT swizzled store: row = nt*16+l16 (row&7 = l16&7)
                int usw = (((wave * 2 + (quad >> 1)) ^ (l16 & 7)) << 3) + ((quad & 1) << 2);
#pragma unroll
                for (int nt = 0; nt < 8; ++nt) {
                    short4v w4;
#pragma unroll
                    for (int e = 0; e < 4; ++e) w4[e] = f2bf(acc[nt][e]);
                    *(short4v*)(UvT + (cb * 128 + nt * 16 + l16) * 64 + usw) = w4;
                }
            } else {
#pragma unroll
                for (int nt = 0; nt < 8; ++nt)
#pragma unroll
                    for (int r = 0; r < 4; ++r) {
                        int trow = wave * 16 + quad * 4 + r;
                        int colsw = (((nt * 2 + (l16 >> 3)) ^ (trow & 7)) << 3) + (l16 & 7);
                        Tk[(cb * 64 + trow) * 128 + colsw] = f2bf(acc[nt][r]);
                    }
            }
        }
    }
}

// ---------------- chunk prep B: W, Qg, KtilT, gam63 ----------------
// Wb_/Qg/KtT stores chunk-XOR-swizzled (ch ^= row&7) to match seq_kernel's LDS reads.
__global__ __launch_bounds__(256) void prepb_kernel(
    const short* __restrict__ qn, const short* __restrict__ kn,
    const float* __restrict__ gdec,
    short* __restrict__ Wb_, short* __restrict__ Qg,
    short* __restrict__ KtT, float* __restrict__ gam63) {
    __shared__ short KT[128][72];
    __shared__ float Ls[64];
    int wg = blockIdx.x;
    int c = wg & 31, bh = wg >> 5;
    int b = bh >> 4, h = bh & 15;
    int tid = threadIdx.x, wave = tid >> 6, lane = tid & 63;
    int quad = lane >> 4, l16 = lane & 15;
    const short* Qb = qn + ((size_t)(b * S_LEN + c * CT)) * KD + h * 128;
    const short* Kb = kn + ((size_t)(b * S_LEN + c * CT)) * KD + h * 128;

    if (wave == 0) {
        float lg = __logf(gdec[((size_t)(b * S_LEN + c * CT) + lane) * NH + h]);
#pragma unroll
        for (int off = 1; off < 64; off <<= 1) {
            float y = __shfl_up(lg, off);
            if (lane >= off) lg += y;
        }
        Ls[lane] = lg;
    }
    __syncthreads();
    size_t cb = (size_t)(bh * NC + c);
    if (tid == 0) gam63[cb] = __expf(Ls[63]);

    // W = mask_{i<=t} e^{L_t-L_i} (q_t.k_i)
    {
        floatx4 acc[4];
#pragma unroll
        for (int i = 0; i < 4; ++i) acc[i] = (floatx4){0.f, 0.f, 0.f, 0.f};
        for (int ks = 0; ks < 4; ++ks) {
            short8 af = *(const short8*)(Qb + (size_t)(wave * 16 + l16) * KD + ks * 32 + quad * 8);
#pragma unroll
            for (int it = 0; it < 4; ++it) {
                short8 bf = *(const short8*)(Kb + (size_t)(it * 16 + l16) * KD + ks * 32 + quad * 8);
                acc[it] = MFMA(af, bf, acc[it]);
            }
        }
#pragma unroll
        for (int it = 0; it < 4; ++it) {
            int icol = it * 16 + l16;
#pragma unroll
            for (int r = 0; r < 4; ++r) {
                int trow = wave * 16 + quad * 4 + r;
                float v = (icol <= trow) ? __expf(Ls[trow] - Ls[icol]) * acc[it][r] : 0.f;
                int colsw = (((it * 2 + (l16 >> 3)) ^ (trow & 7)) << 3) + (l16 & 7);
                Wb_[(cb * 64 + trow) * 64 + colsw] = f2bf(v);
            }
        }
    }

    // Qg rows (e^{L_t} q_t)  +  stage scaled-K transpose
    {
        int tr = tid >> 2, seg = (tid & 3) * 32;
        float sq = __expf(Ls[tr]);
        float sk = __expf(Ls[63] - Ls[tr]);
#pragma unroll
        for (int j = 0; j < 4; ++j) {
            short8 dq = *(const short8*)(Qb + (size_t)tr * KD + seg + j * 8);
            short8 dk = *(const short8*)(Kb + (size_t)tr * KD + seg + j * 8);
            short8 oq;
#pragma unroll
            for (int e = 0; e < 8; ++e) {
                oq[e] = f2bf(bf2f(dq[e]) * sq);
                KT[seg + j * 8 + e][tr] = f2bf(bf2f(dk[e]) * sk);
            }
            int ch = (tid & 3) * 4 + j;
            *(short8*)(Qg + (cb * 64 + tr) * 128 + ((ch ^ (tr & 7)) << 3)) = oq;
        }
    }
    __syncthreads();
    {
        int dk = tid >> 1, seg = (tid & 1) * 32;
#pragma unroll
        for (int j = 0; j < 4; ++j) {
            short8 v = *(const short8*)&KT[dk][seg + j * 8];
            int ch = (tid & 1) * 4 + j;
            *(short8*)(KtT + (cb * 128 + dk) * 64 + ((ch ^ (dk & 7)) << 3)) = v;
        }
    }
}

// ---------------- sequential chunk pass: LDS double-buffered staging ----------------
// (R4: global_load_lds staging + counted vmcnt(16); verified, seq dropped out of top-5)
__global__ __launch_bounds__(256, 1) void seq_kernel(
    const short* __restrict__ UvT, const short* __restrict__ Tk,
    const short* __restrict__ Wb_, const short* __restrict__ Qg,
    const short* __restrict__ KtT, const float* __restrict__ gam63,
    short* __restrict__ ob) {
    extern __shared__ char smem[];
    const int BUF = 65536;
    const int TKO = 0, QGO = 16384, KTO = 32768, UVO = 49152, WO = 57344;
    short (*ST)[136] = (short (*)[136])(smem + 131072);
    short (*UTs)[72] = (short (*)[72])(smem + 131072 + 17408);

    int wg = blockIdx.x;
    int vh = wg & 1, bh = wg >> 1;
    int b = bh >> 4, h = bh & 15;
    int tid = threadIdx.x, wave = tid >> 6, lane = tid & 63;
    int quad = lane >> 4, l16 = lane & 15;
    int swk = l16 & 7;

    for (int i = tid; i < 64 * 136; i += 256) ((short*)(smem + 131072))[i] = 0;
    floatx4 sacc[8];
#pragma unroll
    for (int i = 0; i < 8; ++i) sacc[i] = (floatx4){0.f, 0.f, 0.f, 0.f};

    size_t cb0 = (size_t)bh * NC;
    int row16 = wave * 16 + l16;
    int chq[4];
#pragma unroll
    for (int ks = 0; ks < 4; ++ks) chq[ks] = (((ks * 4 + quad) ^ swk) << 4);
    int uvoff = (((wave * 2 + (quad >> 1)) ^ swk) << 4) + ((quad & 1) << 3);

#define STAGE_CHUNK(bsel_, c_)                                                       \
    {                                                                                \
        char* dst = smem + (bsel_) * BUF;                                            \
        size_t cbs = cb0 + (c_);                                                     \
        const char* gt = (const char*)Tk  + cbs * 16384 + wave * 1024 + lane * 16;   \
        const char* gq = (const char*)Qg  + cbs * 16384 + wave * 1024 + lane * 16;   \
        const char* gk = (const char*)KtT + cbs * 16384 + wave * 1024 + lane * 16;   \
        const char* gu = (const char*)UvT + cbs * 16384 + (size_t)vh * 8192 + wave * 1024 + lane * 16; \
        const char* gw = (const char*)Wb_ + cbs * 8192  + wave * 1024 + lane * 16;   \
        _Pragma("unroll")                                                            \
        for (int it = 0; it < 4; ++it) {                                             \
            load_lds16(gt + it * 4096, dst + TKO + it * 4096 + wave * 1024);         \
            load_lds16(gq + it * 4096, dst + QGO + it * 4096 + wave * 1024);         \
            load_lds16(gk + it * 4096, dst + KTO + it * 4096 + wave * 1024);         \
        }                                                                            \
        _Pragma("unroll")                                                            \
        for (int it = 0; it < 2; ++it) {                                             \
            load_lds16(gu + it * 4096, dst + UVO + it * 4096 + wave * 1024);         \
            load_lds16(gw + it * 4096, dst + WO  + it * 4096 + wave * 1024);         \
        }                                                                            \
    }

    STAGE_CHUNK(0, 0)
    float gamA = gam63[cb0];
    __syncthreads();   // drains stage(0) + ST zero-init, once

#pragma unroll 1
    for (int c = 0; c < NC; ++c) {
        float gamN = 0.f;
        if (c + 1 < NC) {
            gamN = gam63[cb0 + c + 1];
            STAGE_CHUNK((c + 1) & 1, c + 1)
        }
        const char* bufc = smem + (c & 1) * BUF;

        floatx4 uacc[4], oacc[4];
#pragma unroll
        for (int vt = 0; vt < 4; ++vt) {
            short4v u4 = *(const short4v*)(bufc + UVO + (vt * 16 + l16) * 128 + uvoff);
            floatx4 a;
#pragma unroll
            for (int e = 0; e < 4; ++e) a[e] = bf2f(u4[e]);
            uacc[vt] = a;
            oacc[vt] = (floatx4){0.f, 0.f, 0.f, 0.f};
        }
#pragma unroll
        for (int ks = 0; ks < 4; ++ks) {
            short8 tkf = *(const short8*)(bufc + TKO + row16 * 256 + chq[ks]);
            short8 qgf = *(const short8*)(bufc + QGO + row16 * 256 + chq[ks]);
            short8 afT = neg8(tkf);
#pragma unroll
            for (int vt = 0; vt < 4; ++vt) {
                short8 bf = *(const short8*)&ST[vt * 16 + l16][ks * 32 + quad * 8];
                uacc[vt] = MFMA(afT, bf, uacc[vt]);
                oacc[vt] = MFMA(qgf, bf, oacc[vt]);
            }
        }
#pragma unroll
        for (int vt = 0; vt < 4; ++vt) {
            short4v w4;
#pragma unroll
            for (int e = 0; e < 4; ++e) w4[e] = f2bf(uacc[vt][e]);
            *(short4v*)&UTs[vt * 16 + l16][wave * 16 + quad * 4] = w4;
        }
        lds_barrier();
#pragma unroll
        for (int ks = 0; ks < 2; ++ks) {
            short8 wf = *(const short8*)(bufc + WO + row16 * 128 + chq[ks]);
#pragma unroll
            for (int vt = 0; vt < 4; ++vt) {
                short8 bf = *(const short8*)&UTs[vt * 16 + l16][ks * 32 + quad * 8];
                oacc[vt] = MFMA(wf, bf, oacc[vt]);
            }
        }
#pragma unroll
        for (int vt = 0; vt < 4; ++vt)
#pragma unroll
            for (int r = 0; r < 4; ++r) {
                int m = b * S_LEN + c * CT + wave * 16 + quad * 4 + r;
                ob[(size_t)m * VD + h * 128 + vh * 64 + vt * 16 + l16] = f2bf(oacc[vt][r]);
            }
#pragma unroll
        for (int dt = 0; dt < 8; ++dt)
#pragma unroll
            for (int e = 0; e < 4; ++e) sacc[dt][e] *= gamA;
#pragma unroll
        for (int ks = 0; ks < 2; ++ks) {
            short8 af = *(const short8*)&UTs[wave * 16 + l16][ks * 32 + quad * 8];
#pragma unroll
            for (int dt = 0; dt < 8; ++dt) {
                short8 ktf = *(const short8*)(bufc + KTO + (dt * 16 + l16) * 128 + chq[ks]);
                sacc[dt] = MFMA(af, ktf, sacc[dt]);
            }
        }
#pragma unroll
        for (int dt = 0; dt < 8; ++dt)
#pragma unroll
            for (int r = 0; r < 4; ++r)
                ST[wave * 16 + quad * 4 + r][dt * 16 + l16] = f2bf(sacc[dt][r]);

        if (c + 1 < NC) {
            asm volatile("s_waitcnt lgkmcnt(0)" ::: "memory");
            VM(16)      // stage(c+1) drained; ob stores (16 newest) stay in flight
            __builtin_amdgcn_s_barrier();
        }
        gamA = gamN;
    }
#undef STAGE_CHUNK
}

// ---------------- RMSNorm + SiLU gate (bf16 in/out) ----------------
__global__ __launch_bounds__(256) void rms_gate_kernel(
    const short* __restrict__ o, const short* __restrict__ graw,
    const float* __restrict__ nw, short* __restrict__ og) {
    __shared__ float red[4];
    int m = blockIdx.x, t = threadIdx.x;
    short8 a = ((const short8*)(o + (size_t)m * VD))[t];
    float av[8];
#pragma unroll
    for (int i = 0; i < 8; ++i) av[i] = bf2f(a[i]);
    float ss = 0.f;
#pragma unroll
    for (int i = 0; i < 8; ++i) ss += av[i] * av[i];
#pragma unroll
    for (int off = 1; off < 64; off <<= 1) ss += __shfl_xor(ss, off);
    if ((t & 63) == 0) red[t >> 6] = ss;
    __syncthreads();
    float tot = red[0] + red[1] + red[2] + red[3];
    float sc = rsqrtf(tot * (1.f / VD) + 1e-6f);
    short8 gv = ((const short8*)(graw + (size_t)m * VD))[t];
    float4 n0 = ((const float4*)nw)[2 * t];
    float4 n1 = ((const float4*)nw)[2 * t + 1];
    const float* na = (const float*)&n0;
    const float* nb = (const float*)&n1;
    short8 ov;
#pragma unroll
    for (int i = 0; i < 4; ++i) ov[i]     = f2bf(av[i]     * sc * na[i] * silu_f(bf2f(gv[i])));
#pragma unroll
    for (int i = 0; i < 4; ++i) ov[i + 4] = f2bf(av[i + 4] * sc * nb[i] * silu_f(bf2f(gv[i + 4])));
    ((short8*)(og + (size_t)m * VD))[t] = ov;
}

// ---------------- host launcher ----------------
extern "C" void kernel_launch(void* const* d_in, const int* in_sizes, int n_in,
                              void* d_out, int out_size, void* d_ws, size_t ws_size,
                              hipStream_t stream) {
    const float* x    = (const float*)d_in[0];
    const float* Wq   = (const float*)d_in[1];
    const float* Wk   = (const float*)d_in[2];
    const float* Wv   = (const float*)d_in[3];
    const float* Wa   = (const float*)d_in[4];
    const float* Wb   = (const float*)d_in[5];
    const float* Wg   = (const float*)d_in[6];
    const float* Wo   = (const float*)d_in[7];
    const float* cwq  = (const float*)d_in[8];
    const float* cbq  = (const float*)d_in[9];
    const float* cwk  = (const float*)d_in[10];
    const float* cbk  = (const float*)d_in[11];
    const float* cwv  = (const float*)d_in[12];
    const float* cbv  = (const float*)d_in[13];
    const float* Alog = (const float*)d_in[14];
    const float* dtb  = (const float*)d_in[15];
    const float* nw   = (const float*)d_in[16];

    char* ws = (char*)d_ws;
    short* Wob = (short*)(ws);
    short* xb  = (short*)(ws + 8 * MB);
    short* Wqb = (short*)(ws + 24 * MB);
    short* Wkb = (short*)(ws + 32 * MB);
    short* Wvb = (short*)(ws + 40 * MB);
    short* Wgb = (short*)(ws + 48 * MB);
    short* qrb = (short*)(ws + 56 * MB);
    short* krb = (short*)(ws + 72 * MB);
    short* vrb = (short*)(ws + 88 * MB);
    short* grb = (short*)(ws + 104 * MB);
    short* qnb = (short*)(ws + 8 * MB);
    short* knb = (short*)(ws + 24 * MB);
    short* vnb = (short*)(ws + 40 * MB);
    float* gdec = (float*)(ws + 120 * MB);
    float* beta = (float*)(ws + 120 * MB + 262144);
    short* ob  = qrb;   // reuse
    short* ogb = krb;   // reuse
    // chunked-scan buffers
    short* UvT  = (short*)(ws + 121 * MB);   // [1024][128][64]
    short* Tkb  = (short*)(ws + 137 * MB);   // [1024][64][128]
    short* Wbuf = (short*)(ws + 153 * MB);   // [1024][64][64]
    short* Qgb  = (short*)(ws + 161 * MB);   // [1024][64][128]
    short* KtT  = (short*)(ws + 177 * MB);   // [1024][128][64]
    float* gm63 = (float*)(ws + 193 * MB);   // [1024]

    // one-time: allow large dynamic LDS
    static bool attr_done = false;
    if (!attr_done) {
        hipFuncSetAttribute((const void*)gemm8_qkvg,
                            hipFuncAttributeMaxDynamicSharedMemorySize, 131072);
        hipFuncSetAttribute((const void*)gemm8_out,
                            hipFuncAttributeMaxDynamicSharedMemorySize, 131072);
        hipFuncSetAttribute((const void*)seq_kernel,
                            hipFuncAttributeMaxDynamicSharedMemorySize, 157696);
        attr_done = true;
    }

    // 1. fp32 -> bf16 conversions (single launch)
    cvt_all_kernel<<<dim3(4096, 6), 256, 0, stream>>>(x, Wq, Wk, Wv, Wg, Wo,
                                                      xb, Wqb, Wkb, Wvb, Wgb, Wob);

    // 2. a/b projection + decay/beta (coalesced 16-lane-group GEMV, no reg x-cache)
    ab_kernel<<<512, 256, 0, stream>>>(x, Wa, Wb, Alog, dtb, gdec, beta);

    // 3. fused q/k/v/gate projections (256^2 frag-prefetch pipeline, 128 KiB LDS)
    gemm8_qkvg<<<dim3(128, 1, 4), 512, 131072, stream>>>(xb, Wqb, Wkb, Wvb, Wgb,
                                                         qrb, krb, vrb, grb);

    // 4. causal conv + SiLU + l2norm
    conv_kernel<<<16384, 256, 0, stream>>>(qrb, krb, vrb,
                                           cwq, cbq, cwk, cbk, cwv, cbv, qnb, knb, vnb);

    // 5. chunked delta-rule
    solve_kernel<<<2048, 256, 0, stream>>>(knb, vnb, gdec, beta, UvT, Tkb);
    prepb_kernel<<<1024, 256, 0, stream>>>(qnb, knb, gdec, Wbuf, Qgb, KtT, gm63);
    seq_kernel<<<64, 256, 157696, stream>>>(UvT, Tkb, Wbuf, Qgb, KtT, gm63, ob);

    // 6. RMSNorm + SiLU gate
    rms_gate_kernel<<<4096, 256, 0, stream>>>(ob, grb, nw, ogb);

    // 7. output projection (256^2 frag-prefetch pipeline, fp32 out)
    gemm8_out<<<dim3(128, 1, 1), 512, 131072, stream>>>(ogb, Wob, (float*)d_out);
}

// Round 9
// 632.874 us; speedup vs baseline: 1.7286x; 1.0489x over previous
//
#include <hip/hip_runtime.h>

// ---------------- problem constants ----------------
#define S_LEN   2048
#define NH      16
#define DIM     2048
#define KD      2048
#define VD      2048
#define MB      1048576ull
#define CT      64     // chunk length
#define NC      32     // chunks per sequence

typedef short  short8  __attribute__((ext_vector_type(8)));
typedef short  short4v __attribute__((ext_vector_type(4)));
typedef float  floatx4 __attribute__((ext_vector_type(4)));

#define MFMA(a, b, c) __builtin_amdgcn_mfma_f32_16x16x32_bf16((a), (b), (c), 0, 0, 0)

// fp32 -> bf16, round-to-nearest-even
__device__ inline short f2bf(float x) {
    unsigned u = __float_as_uint(x);
    unsigned r = (u + 0x7fffu + ((u >> 16) & 1u)) >> 16;
    return (short)r;
}
__device__ inline float bf2f(short s) {
    return __uint_as_float(((unsigned)(unsigned short)s) << 16);
}
__device__ inline float silu_f(float x) { return x / (1.f + __expf(-x)); }

__device__ inline short8 neg8(short8 a) {
    unsigned* p = (unsigned*)&a;
    p[0] ^= 0x80008000u; p[1] ^= 0x80008000u;
    p[2] ^= 0x80008000u; p[3] ^= 0x80008000u;
    return a;
}

// async global->LDS, 16B per lane; LDS dest is wave-uniform base (+lane*16 implicit)
__device__ inline void load_lds16(const void* g, void* l) {
    __builtin_amdgcn_global_load_lds(
        (const __attribute__((address_space(1))) unsigned int*)g,
        (__attribute__((address_space(3))) unsigned int*)l, 16, 0, 0);
}

__device__ inline void store_c(float* C, size_t idx, float v) { C[idx] = v; }
__device__ inline void store_c(short* C, size_t idx, float v) { C[idx] = f2bf(v); }

// LDS-only barrier (no vmcnt drain)
__device__ __forceinline__ void lds_barrier() {
    asm volatile("s_waitcnt lgkmcnt(0)" ::: "memory");
    __builtin_amdgcn_s_barrier();
}

// Boundary barrier for the GEMM pipeline: lgkmcnt(0) before s_barrier guarantees every
// wave's issued ds_reads of the retiring buffer completed before any wave can DMA over
// it (cross-wave WAR).  Memory-clobber asm on both sides pins LDS ops against motion
// across the barrier.
__device__ __forceinline__ void boundary_barrier() {
    asm volatile("s_waitcnt lgkmcnt(0)" ::: "memory");
    __builtin_amdgcn_s_barrier();
    asm volatile("" ::: "memory");
}

#define VM(n_) asm volatile("s_waitcnt vmcnt(" #n_ ")" ::: "memory");

// ---------------- fp32 -> bf16 conversion (all 6 tensors, one launch) ----------------
__global__ __launch_bounds__(256) void cvt_all_kernel(
    const float* __restrict__ x,  const float* __restrict__ Wq,
    const float* __restrict__ Wk, const float* __restrict__ Wv,
    const float* __restrict__ Wg, const float* __restrict__ Wo,
    short* __restrict__ xb,  short* __restrict__ Wqb, short* __restrict__ Wkb,
    short* __restrict__ Wvb, short* __restrict__ Wgb, short* __restrict__ Wob) {
    const float* in; short* out; int n8;
    switch (blockIdx.y) {
        case 0:  in = x;  out = xb;  n8 = 1048576; break;
        case 1:  in = Wq; out = Wqb; n8 = 524288;  break;
        case 2:  in = Wk; out = Wkb; n8 = 524288;  break;
        case 3:  in = Wv; out = Wvb; n8 = 524288;  break;
        case 4:  in = Wg; out = Wgb; n8 = 524288;  break;
        default: in = Wo; out = Wob; n8 = 524288;  break;
    }
    int i = blockIdx.x * 256 + threadIdx.x;
    if (i >= n8) return;
    float4 a = ((const float4*)in)[2 * i];
    float4 b = ((const float4*)in)[2 * i + 1];
    short8 o;
    o[0] = f2bf(a.x); o[1] = f2bf(a.y); o[2] = f2bf(a.z); o[3] = f2bf(a.w);
    o[4] = f2bf(b.x); o[5] = f2bf(b.y); o[6] = f2bf(b.z); o[7] = f2bf(b.w);
    ((short8*)out)[i] = o;
}

// ---------------- 256^2 bf16 GEMM, register-fragment-prefetch pipeline ----------------
// (R5, verified: 1 barrier/sub-tile, frag prefetch 1 phase ahead, counted vmcnt(8);
//  swizzle chunk ^= (row>>1)&3, conflicts == 0 measured R4.)

#define STAGE8(s_, isB_)                                                     \
    {                                                                        \
        const char* gsrc = (isB_) ? (const char*)Bw : (const char*)A;        \
        int t0 = (isB_) ? n0 : m0;                                           \
        char* dbase = smem + ((s_) & 3) * 32768 + (isB_) * 16384;            \
        _Pragma("unroll")                                                    \
        for (int ld = 0; ld < 2; ++ld) {                                     \
            int ch = ld * 8 + wave;                                          \
            int Pl = (ch << 10) + (lane << 4);                               \
            int Q  = Pl ^ (((lane >> 3) & 3) << 4);                          \
            const char* src = gsrc + ((size_t)(t0 + (Q >> 6)) << 12)         \
                              + ((size_t)(s_) << 6) + (Q & 63);              \
            load_lds16(src, dbase + (ch << 10));                             \
        }                                                                    \
    }

#define RD_AF(dst_, s_, qm_)                                                 \
    {                                                                        \
        const char* sb_ = smem + ((s_) & 3) * 32768;                         \
        _Pragma("unroll")                                                    \
        for (int mf = 0; mf < 4; ++mf)                                       \
            dst_[mf] = *(const short8*)(sb_ +                                \
                ((rowA_base + (qm_) * 64 + mf * 16) << 6) + qsw);            \
    }

#define RD_BF(dst_, s_)                                                      \
    {                                                                        \
        const char* sb_ = smem + ((s_) & 3) * 32768 + 16384;                 \
        _Pragma("unroll")                                                    \
        for (int nf = 0; nf < 4; ++nf)                                       \
            dst_[nf] = *(const short8*)(sb_ +                                \
                ((rowB_base + nf * 16) << 6) + qsw);                         \
    }

#define MM(qm_, af_, bf_)                                                    \
    {                                                                        \
        __builtin_amdgcn_s_setprio(1);                                       \
        _Pragma("unroll")                                                    \
        for (int mf = 0; mf < 4; ++mf)                                       \
            _Pragma("unroll")                                                \
            for (int nf = 0; nf < 4; ++nf)                                   \
                acc[(qm_) * 4 + mf][nf] =                                    \
                    MFMA(af_[mf], bf_[nf], acc[(qm_) * 4 + mf][nf]);         \
        __builtin_amdgcn_s_setprio(0);                                       \
    }

template <typename OutT>
__device__ __forceinline__ void gemm8_tile(const short* __restrict__ A,
                                           const short* __restrict__ Bw,
                                           OutT* __restrict__ C, char* smem) {
    int x  = blockIdx.x;
    int xs = (x & 7) * 16 + (x >> 3);            // XCD-chunked swizzle (128 % 8 == 0)
    int m0 = (xs >> 3) * 256;                    // 16 m-tiles
    int n0 = (xs & 7) * 256;                     // 8 n-tiles
    int tid  = threadIdx.x;
    int wave = tid >> 6, lane = tid & 63;
    int l16  = lane & 15, quad = lane >> 4;
    int wm = wave >> 2, wn = wave & 3;
    int qsw = ((quad ^ ((l16 >> 1) & 3)) << 4);  // read-side swizzled 16B-chunk offset
    int rowA_base = wm * 128 + l16;
    int rowB_base = wn * 64 + l16;

    floatx4 acc[8][4];
#pragma unroll
    for (int i = 0; i < 8; ++i)
#pragma unroll
        for (int j = 0; j < 4; ++j) acc[i][j] = (floatx4){0.f, 0.f, 0.f, 0.f};
    short8 af0[4], af1[4], bfA[4], bfB[4];

    // prologue: stage sub-tiles 0,1,2; drain s0; publish; prefetch first fragments
    STAGE8(0, 0) STAGE8(0, 1)
    STAGE8(1, 0) STAGE8(1, 1)
    STAGE8(2, 0) STAGE8(2, 1)
    VM(8)
    boundary_barrier();
    RD_AF(af0, 0, 0) RD_BF(bfA, 0)

    // steady state: sub-tiles 0..59, unrolled x2 for bfA/bfB parity
#pragma unroll 1
    for (int sp = 0; sp < 60; sp += 2) {
        // s = sp (even, bf = bfA)
        STAGE8(sp + 3, 0)
        RD_AF(af1, sp, 1)
        MM(0, af0, bfA)
        STAGE8(sp + 3, 1)
        VM(8)
        boundary_barrier();
        RD_AF(af0, sp + 1, 0) RD_BF(bfB, sp + 1)
        MM(1, af1, bfA)
        // s = sp+1 (odd, bf = bfB)
        STAGE8(sp + 4, 0)
        RD_AF(af1, sp + 1, 1)
        MM(0, af0, bfB)
        STAGE8(sp + 4, 1)
        VM(8)
        boundary_barrier();
        RD_AF(af0, sp + 2, 0) RD_BF(bfA, sp + 2)
        MM(1, af1, bfB)
    }

    // s = 60 (even): stage final sub-tile 63
    STAGE8(63, 0)
    RD_AF(af1, 60, 1)
    MM(0, af0, bfA)
    STAGE8(63, 1)
    VM(8)            // outstanding {61,62,63}=12 -> drains 61
    boundary_barrier();
    RD_AF(af0, 61, 0) RD_BF(bfB, 61)
    MM(1, af1, bfA)
    // s = 61 (odd): no stage
    RD_AF(af1, 61, 1)
    MM(0, af0, bfB)
    VM(4)            // outstanding {62,63}=8 -> drains 62
    boundary_barrier();
    RD_AF(af0, 62, 0) RD_BF(bfA, 62)
    MM(1, af1, bfB)
    // s = 62 (even)
    RD_AF(af1, 62, 1)
    MM(0, af0, bfA)
    VM(0)            // drains 63
    boundary_barrier();
    RD_AF(af0, 63, 0) RD_BF(bfB, 63)
    MM(1, af1, bfA)
    // s = 63 (odd)
    RD_AF(af1, 63, 1)
    MM(0, af0, bfB)
    MM(1, af1, bfB)

    // epilogue: C write
#pragma unroll
    for (int i = 0; i < 8; ++i) {
        int row0 = m0 + wm * 128 + (i >> 2) * 64 + (i & 3) * 16 + quad * 4;
#pragma unroll
        for (int nf = 0; nf < 4; ++nf) {
            int col = n0 + wn * 64 + nf * 16 + l16;
#pragma unroll
            for (int r = 0; r < 4; ++r)
                store_c(C, (size_t)(row0 + r) * 2048 + col, acc[i][nf][r]);
        }
    }
}

__global__ __launch_bounds__(512, 2) void gemm8_qkvg(const short* __restrict__ A,
    const short* __restrict__ B0, const short* __restrict__ B1,
    const short* __restrict__ B2, const short* __restrict__ B3,
    short* __restrict__ C0, short* __restrict__ C1,
    short* __restrict__ C2, short* __restrict__ C3) {
    extern __shared__ char smem[];
    const short* Bw; short* C;
    switch (blockIdx.z) {
        case 0:  Bw = B0; C = C0; break;
        case 1:  Bw = B1; C = C1; break;
        case 2:  Bw = B2; C = C2; break;
        default: Bw = B3; C = C3; break;
    }
    gemm8_tile<short>(A, Bw, C, smem);
}

// ---------------- output GEMM: 128x256 tile, 256 blocks (R9) ----------------
// R8 post-mortem: the 256^2-tile gemm8_out launched only 128 blocks on 256 CUs --
// half the GPU provably idle. This variant: BM=128, BN=256 -> grid 32x8 = 256
// blocks, 1/CU. 8 waves as 2(M) x 4(N), per-wave 64x64 out (acc 64 VGPR). LDS 4
// sub-buffers x 24KB (A 8KB + B 16KB) = 96KB. 3 loads/thread/sub-tile -> counted
// VM(6) steady (drains s+1), VM(3)/VM(0) tail. Same verified swizzle family:
// stage key = (D>>7)&3 = (lane>>3)&3 for all loads here (A: D=wave*1024+lane*16;
// B adds ld*8192 = 0 mod 512); read qsw identical (fragment rows = 16k + l16).
__global__ __launch_bounds__(512, 2) void gemm_out128(const short* __restrict__ A,
    const short* __restrict__ Bw, float* __restrict__ C) {
    extern __shared__ char smem[];
    int x   = blockIdx.x;
    int swz = (x & 7) * 32 + (x >> 3);          // bijective: 256 = 8 XCDs x 32
    int m0  = (swz >> 3) * 128;                  // 32 m-tiles
    int n0  = (swz & 7) * 256;                   // 8 n-tiles
    int tid = threadIdx.x;
    int wave = tid >> 6, lane = tid & 63;
    int l16 = lane & 15, quad = lane >> 4;
    int wm = wave >> 2, wn = wave & 3;           // 2 x 4
    int qsw = ((quad ^ ((l16 >> 1) & 3)) << 4);
    int rowA = wm * 64 + l16;
    int rowB = wn * 64 + l16;

    floatx4 acc[4][4];
#pragma unroll
    for (int i = 0; i < 4; ++i)
#pragma unroll
        for (int j = 0; j < 4; ++j) acc[i][j] = (floatx4){0.f, 0.f, 0.f, 0.f};
    short8 afA[4], bfA[4], afB[4], bfB[4];

#define STG128(s_)                                                            \
    {                                                                         \
        char* dbase = smem + ((s_) & 3) * 24576;                              \
        {                                                                     \
            int D = (wave << 10) + (lane << 4);                               \
            int Q = D ^ (((lane >> 3) & 3) << 4);                             \
            const char* src = (const char*)A + ((size_t)(m0 + (Q >> 6)) << 12)\
                              + ((size_t)(s_) << 6) + (Q & 63);               \
            load_lds16(src, dbase + (wave << 10));                            \
        }                                                                     \
        _Pragma("unroll")                                                     \
        for (int ld = 0; ld < 2; ++ld) {                                      \
            int D = (ld << 13) + (wave << 10) + (lane << 4);                  \
            int Q = D ^ (((lane >> 3) & 3) << 4);                             \
            const char* src = (const char*)Bw + ((size_t)(n0 + (Q >> 6)) << 12)\
                              + ((size_t)(s_) << 6) + (Q & 63);               \
            load_lds16(src, dbase + 8192 + (ld << 13) + (wave << 10));        \
        }                                                                     \
    }

#define RD128(af_, bf_, s_)                                                   \
    {                                                                         \
        const char* sb_ = smem + ((s_) & 3) * 24576;                          \
        _Pragma("unroll")                                                     \
        for (int f = 0; f < 4; ++f) {                                         \
            af_[f] = *(const short8*)(sb_ + ((rowA + f * 16) << 6) + qsw);    \
            bf_[f] = *(const short8*)(sb_ + 8192 + ((rowB + f * 16) << 6) + qsw); \
        }                                                                     \
    }

#define MM128(af_, bf_)                                                       \
    {                                                                         \
        __builtin_amdgcn_s_setprio(1);                                        \
        _Pragma("unroll")                                                     \
        for (int i = 0; i < 4; ++i)                                           \
            _Pragma("unroll")                                                 \
            for (int j = 0; j < 4; ++j)                                       \
                acc[i][j] = MFMA(af_[i], bf_[j], acc[i][j]);                  \
        __builtin_amdgcn_s_setprio(0);                                        \
    }

    // prologue: stage 0,1,2 (9 loads/thread); drain s0; publish; read s0 frags
    STG128(0) STG128(1) STG128(2)
    VM(6)
    boundary_barrier();
    RD128(afA, bfA, 0)

#pragma unroll 1
    for (int s = 0; s < 60; s += 2) {
        STG128(s + 3)        // outstanding {s+1,s+2,s+3} = 9
        VM(6)                // drains s+1
        boundary_barrier();
        RD128(afB, bfB, s + 1)
        MM128(afA, bfA)      // sub-tile s
        STG128(s + 4)
        VM(6)                // drains s+2
        boundary_barrier();
        RD128(afA, bfA, s + 2)
        MM128(afB, bfB)      // sub-tile s+1
    }
    // s = 60
    STG128(63)               // outstanding {61,62,63} = 9
    VM(6)                    // drains 61
    boundary_barrier();
    RD128(afB, bfB, 61)
    MM128(afA, bfA)
    // s = 61
    VM(3)                    // drains 62
    boundary_barrier();
    RD128(afA, bfA, 62)
    MM128(afB, bfB)
    // s = 62
    VM(0)                    // drains 63
    boundary_barrier();
    RD128(afB, bfB, 63)
    MM128(afA, bfA)
    // s = 63
    MM128(afB, bfB)

    // epilogue: fp32 C write
#pragma unroll
    for (int i = 0; i < 4; ++i) {
        int row0 = m0 + wm * 64 + i * 16 + quad * 4;
#pragma unroll
        for (int j = 0; j < 4; ++j) {
            int col = n0 + wn * 64 + j * 16 + l16;
#pragma unroll
            for (int r = 0; r < 4; ++r)
                C[(size_t)(row0 + r) * 2048 + col] = acc[i][j][r];
        }
    }
#undef STG128
#undef RD128
#undef MM128
}

// ---------------- a/b projection + decay/beta transform ----------------
// (R8, verified: coalesced 16-lane-group GEMV, no reg x-cache, conflicts 0)
__global__ __launch_bounds__(256) void ab_kernel(const float* __restrict__ x,
    const float* __restrict__ Wa, const float* __restrict__ Wb,
    const float* __restrict__ Alog, const float* __restrict__ dtb,
    float* __restrict__ gdec, float* __restrict__ beta) {
    int t = threadIdx.x;
    int wave = t >> 6, lane = t & 63;
    int l16 = lane & 15, grp = lane >> 4;
    int m0 = (blockIdx.x * 4 + wave) * 2;
    const float4* x0 = (const float4*)(x + (size_t)m0 * DIM);
    const float4* x1 = (const float4*)(x + (size_t)(m0 + 1) * DIM);

#pragma unroll 1
    for (int p = 0; p < 8; ++p) {
        int c = p * 4 + grp;
        const float4* wr = (const float4*)((c < 16) ? (Wa + (size_t)c * DIM)
                                                    : (Wb + (size_t)(c - 16) * DIM));
        float s0 = 0.f, s1 = 0.f;
#pragma unroll 8
        for (int j = 0; j < 32; ++j) {
            float4 wv = wr[j * 16 + l16];
            float4 a0 = x0[j * 16 + l16];
            float4 a1 = x1[j * 16 + l16];
            s0 += a0.x * wv.x + a0.y * wv.y + a0.z * wv.z + a0.w * wv.w;
            s1 += a1.x * wv.x + a1.y * wv.y + a1.z * wv.z + a1.w * wv.w;
        }
#pragma unroll
        for (int off = 1; off < 16; off <<= 1) {
            s0 += __shfl_xor(s0, off);
            s1 += __shfl_xor(s1, off);
        }
        if (l16 < 2) {
            int m = m0 + l16;
            float sv = l16 ? s1 : s0;
            if (c < 16) {
                float sp = sv + dtb[c];
                float softp = (sp > 20.f) ? sp : log1pf(expf(sp));
                gdec[(size_t)m * NH + c] = expf(-expf(Alog[c]) * softp);
            } else {
                beta[(size_t)m * NH + (c - 16)] = 1.f / (1.f + expf(-sv));
            }
        }
    }
}

// ---------------- causal conv (K=4) + SiLU + l2norm(q,k)  (bf16 in/out) ----------------
__global__ __launch_bounds__(256) void conv_kernel(
    const short* __restrict__ qr, const short* __restrict__ kr, const short* __restrict__ vr,
    const float* __restrict__ cwq, const float* __restrict__ cbq,
    const float* __restrict__ cwk, const float* __restrict__ cbk,
    const float* __restrict__ cwv, const float* __restrict__ cbv,
    short* __restrict__ qn, short* __restrict__ kn, short* __restrict__ vc) {
    int gw   = blockIdx.x * 4 + (threadIdx.x >> 6);
    int lane = threadIdx.x & 63;
    int h  = gw & (NH - 1);
    int m  = gw >> 4;
    int tt = m & (S_LEN - 1);
    int c  = h * 128 + lane * 2;
    size_t rowbase = (size_t)m * KD + c;

    float4 wq0 = ((const float4*)cwq)[c], wq1 = ((const float4*)cwq)[c + 1];
    float4 wk0 = ((const float4*)cwk)[c], wk1 = ((const float4*)cwk)[c + 1];
    float4 wv0 = ((const float4*)cwv)[c], wv1 = ((const float4*)cwv)[c + 1];
    float q0 = cbq[c], q1 = cbq[c + 1];
    float k0 = cbk[c], k1 = cbk[c + 1];
    float v0 = cbv[c], v1 = cbv[c + 1];
    const float* wq0a = (const float*)&wq0; const float* wq1a = (const float*)&wq1;
    const float* wk0a = (const float*)&wk0; const float* wk1a = (const float*)&wk1;
    const float* wv0a = (const float*)&wv0; const float* wv1a = (const float*)&wv1;
#pragma unroll
    for (int j = 0; j < 4; ++j) {
        int ts = tt - 3 + j;
        if (ts >= 0) {
            long long rb = (long long)rowbase + (long long)(j - 3) * KD;
            unsigned uq = *(const unsigned*)(qr + rb);
            unsigned uk = *(const unsigned*)(kr + rb);
            unsigned uv = *(const unsigned*)(vr + rb);
            q0 += bf2f((short)(uq & 0xffff)) * wq0a[j]; q1 += bf2f((short)(uq >> 16)) * wq1a[j];
            k0 += bf2f((short)(uk & 0xffff)) * wk0a[j]; k1 += bf2f((short)(uk >> 16)) * wk1a[j];
            v0 += bf2f((short)(uv & 0xffff)) * wv0a[j]; v1 += bf2f((short)(uv >> 16)) * wv1a[j];
        }
    }
    q0 = silu_f(q0); q1 = silu_f(q1);
    k0 = silu_f(k0); k1 = silu_f(k1);
    v0 = silu_f(v0); v1 = silu_f(v1);

    float sq = q0 * q0 + q1 * q1;
    float sk = k0 * k0 + k1 * k1;
#pragma unroll
    for (int off = 1; off < 64; off <<= 1) {
        sq += __shfl_xor(sq, off);
        sk += __shfl_xor(sk, off);
    }
    float iq = 1.f / fmaxf(sqrtf(sq), 1e-12f);
    float ik = 1.f / fmaxf(sqrtf(sk), 1e-12f);
    unsigned oq = (unsigned)(unsigned short)f2bf(q0 * iq) | ((unsigned)(unsigned short)f2bf(q1 * iq) << 16);
    unsigned ok = (unsigned)(unsigned short)f2bf(k0 * ik) | ((unsigned)(unsigned short)f2bf(k1 * ik) << 16);
    unsigned ov = (unsigned)(unsigned short)f2bf(v0)      | ((unsigned)(unsigned short)f2bf(v1)      << 16);
    *(unsigned*)(qn + rowbase) = oq;
    *(unsigned*)(kn + rowbase) = ok;
    *(unsigned*)(vc + rowbase) = ov;
}

// ---------------- chunked delta-rule: per-chunk solve  ----------------
// NOTE: Tk and UvT global stores are chunk-XOR-swizzled (ch ^= row&7 on 16B chunks)
// so seq_kernel can global_load_lds them linearly and ds_read conflict-free.
__global__ __launch_bounds__(256) void solve_kernel(
    const short* __restrict__ kn, const short* __restrict__ vn,
    const float* __restrict__ gdec, const float* __restrict__ beta,
    short* __restrict__ UvT, short* __restrict__ Tk) {
    __shared__ short Pn[64][72];
    __shared__ short Pt[64][72];
    __shared__ short UT[128][72];
    __shared__ float Ls[64];
    __shared__ float Bs[64];

    int wg   = blockIdx.x;
    int half = wg & 1;
    int c    = (wg >> 1) & 31;
    int bh   = wg >> 6;
    int b = bh >> 4, h = bh & 15;
    int tid = threadIdx.x;
    int wave = tid >> 6, lane = tid & 63;
    int quad = lane >> 4, l16 = lane & 15;

    const short* Kb = kn + ((size_t)(b * S_LEN + c * CT)) * KD + h * 128;
    const short* Vb = vn + ((size_t)(b * S_LEN + c * CT)) * KD + h * 128;

    if (wave == 0) {
        float lg = __logf(gdec[((size_t)(b * S_LEN + c * CT) + lane) * NH + h]);
#pragma unroll
        for (int off = 1; off < 64; off <<= 1) {
            float y = __shfl_up(lg, off);
            if (lane >= off) lg += y;
        }
        Ls[lane] = lg;
        Bs[lane] = beta[((size_t)(b * S_LEN + c * CT) + lane) * NH + h];
    }
    __syncthreads();

    // build P = -A
    {
        floatx4 acc[4];
#pragma unroll
        for (int i = 0; i < 4; ++i) acc[i] = (floatx4){0.f, 0.f, 0.f, 0.f};
        for (int ks = 0; ks < 4; ++ks) {
            short8 af = *(const short8*)(Kb + (size_t)(wave * 16 + l16) * KD + ks * 32 + quad * 8);
#pragma unroll
            for (int it = 0; it < 4; ++it) {
                short8 bf = *(const short8*)(Kb + (size_t)(it * 16 + l16) * KD + ks * 32 + quad * 8);
                acc[it] = MFMA(af, bf, acc[it]);
            }
        }
#pragma unroll
        for (int it = 0; it < 4; ++it) {
            int icol = it * 16 + l16;
#pragma unroll
            for (int r = 0; r < 4; ++r) {
                int trow = wave * 16 + quad * 4 + r;
                float v = 0.f;
                if (icol < trow) v = -Bs[trow] * __expf(Ls[trow] - Ls[icol]) * acc[it][r];
                short bv = f2bf(v);
                Pn[trow][icol] = bv;
                Pt[icol][trow] = bv;
            }
        }
    }

    // RHS -> UT (transposed [n][t])
    {
        const short* src = half ? Kb : Vb;
        int tr = tid >> 2, seg = (tid & 3) * 32;
        float s = Bs[tr] * (half ? __expf(Ls[tr]) : 1.f);
#pragma unroll
        for (int j = 0; j < 4; ++j) {
            short8 d = *(const short8*)(src + (size_t)tr * KD + seg + j * 8);
#pragma unroll
            for (int e = 0; e < 8; ++e)
                UT[seg + j * 8 + e][tr] = f2bf(bf2f(d[e]) * s);
        }
    }
    __syncthreads();

    // 6 applications U <- U + P U, squaring P between
    for (int iter = 0; iter < 6; ++iter) {
        floatx4 acc[8];
#pragma unroll
        for (int nt = 0; nt < 8; ++nt) {
            short4v u4 = *(const short4v*)&UT[nt * 16 + l16][wave * 16 + quad * 4];
            floatx4 a;
#pragma unroll
            for (int e = 0; e < 4; ++e) a[e] = bf2f(u4[e]);
            acc[nt] = a;
        }
        for (int ks = 0; ks < 2; ++ks) {
            short8 af = *(const short8*)&Pn[wave * 16 + l16][ks * 32 + quad * 8];
#pragma unroll
            for (int nt = 0; nt < 8; ++nt) {
                short8 bf = *(const short8*)&UT[nt * 16 + l16][ks * 32 + quad * 8];
                acc[nt] = MFMA(af, bf, acc[nt]);
            }
        }
        __syncthreads();
        if (iter < 5) {
#pragma unroll
            for (int nt = 0; nt < 8; ++nt) {
                short4v w4;
#pragma unroll
                for (int e = 0; e < 4; ++e) w4[e] = f2bf(acc[nt][e]);
                *(short4v*)&UT[nt * 16 + l16][wave * 16 + quad * 4] = w4;
            }
            floatx4 pacc[4];
#pragma unroll
            for (int it = 0; it < 4; ++it) pacc[it] = (floatx4){0.f, 0.f, 0.f, 0.f};
            for (int ks = 0; ks < 2; ++ks) {
                short8 paf = *(const short8*)&Pn[wave * 16 + l16][ks * 32 + quad * 8];
#pragma unroll
                for (int it = 0; it < 4; ++it) {
                    short8 pbf = *(const short8*)&Pt[it * 16 + l16][ks * 32 + quad * 8];
                    pacc[it] = MFMA(paf, pbf, pacc[it]);
                }
            }
            __syncthreads();
#pragma unroll
            for (int it = 0; it < 4; ++it) {
                int icol = it * 16 + l16;
#pragma unroll
                for (int r = 0; r < 4; ++r) {
                    int trow = wave * 16 + quad * 4 + r;
                    short bv = f2bf(pacc[it][r]);
                    Pn[trow][icol] = bv;
                    Pt[icol][trow] = bv;
                }
            }
            __syncthreads();
        } else {
            size_t cb = (size_t)(bh * NC + c);
            if (half == 0) {
                // UvT swizzled store: row = nt*16+l16 (row&7 = l16&7)
                int usw = (((wave * 2 + (quad >> 1)) ^ (l16 & 7)) << 3) + ((quad & 1) << 2);
#pragma unroll
                for (int nt = 0; nt < 8; ++nt) {
                    short4v w4;
#pragma unroll
                    for (int e = 0; e < 4; ++e) w4[e] = f2bf(acc[nt][e]);
                    *(short4v*)(UvT + (cb * 128 + nt * 16 + l16) * 64 + usw) = w4;
                }
            } else {
#pragma unroll
                for (int nt = 0; nt < 8; ++nt)
#pragma unroll
                    for (int r = 0; r < 4; ++r) {
                        int trow = wave * 16 + quad * 4 + r;
                        int colsw = (((nt * 2 + (l16 >> 3)) ^ (trow & 7)) << 3) + (l16 & 7);
                        Tk[(cb * 64 + trow) * 128 + colsw] = f2bf(acc[nt][r]);
                    }
            }
        }
    }
}

// ---------------- chunk prep B: W, Qg, KtilT, gam63 ----------------
// Wb_/Qg/KtT stores chunk-XOR-swizzled (ch ^= row&7) to match seq_kernel's LDS reads.
__global__ __launch_bounds__(256) void prepb_kernel(
    const short* __restrict__ qn, const short* __restrict__ kn,
    const float* __restrict__ gdec,
    short* __restrict__ Wb_, short* __restrict__ Qg,
    short* __restrict__ KtT, float* __restrict__ gam63) {
    __shared__ short KT[128][72];
    __shared__ float Ls[64];
    int wg = blockIdx.x;
    int c = wg & 31, bh = wg >> 5;
    int b = bh >> 4, h = bh & 15;
    int tid = threadIdx.x, wave = tid >> 6, lane = tid & 63;
    int quad = lane >> 4, l16 = lane & 15;
    const short* Qb = qn + ((size_t)(b * S_LEN + c * CT)) * KD + h * 128;
    const short* Kb = kn + ((size_t)(b * S_LEN + c * CT)) * KD + h * 128;

    if (wave == 0) {
        float lg = __logf(gdec[((size_t)(b * S_LEN + c * CT) + lane) * NH + h]);
#pragma unroll
        for (int off = 1; off < 64; off <<= 1) {
            float y = __shfl_up(lg, off);
            if (lane >= off) lg += y;
        }
        Ls[lane] = lg;
    }
    __syncthreads();
    size_t cb = (size_t)(bh * NC + c);
    if (tid == 0) gam63[cb] = __expf(Ls[63]);

    // W = mask_{i<=t} e^{L_t-L_i} (q_t.k_i)
    {
        floatx4 acc[4];
#pragma unroll
        for (int i = 0; i < 4; ++i) acc[i] = (floatx4){0.f, 0.f, 0.f, 0.f};
        for (int ks = 0; ks < 4; ++ks) {
            short8 af = *(const short8*)(Qb + (size_t)(wave * 16 + l16) * KD + ks * 32 + quad * 8);
#pragma unroll
            for (int it = 0; it < 4; ++it) {
                short8 bf = *(const short8*)(Kb + (size_t)(it * 16 + l16) * KD + ks * 32 + quad * 8);
                acc[it] = MFMA(af, bf, acc[it]);
            }
        }
#pragma unroll
        for (int it = 0; it < 4; ++it) {
            int icol = it * 16 + l16;
#pragma unroll
            for (int r = 0; r < 4; ++r) {
                int trow = wave * 16 + quad * 4 + r;
                float v = (icol <= trow) ? __expf(Ls[trow] - Ls[icol]) * acc[it][r] : 0.f;
                int colsw = (((it * 2 + (l16 >> 3)) ^ (trow & 7)) << 3) + (l16 & 7);
                Wb_[(cb * 64 + trow) * 64 + colsw] = f2bf(v);
            }
        }
    }

    // Qg rows (e^{L_t} q_t)  +  stage scaled-K transpose
    {
        int tr = tid >> 2, seg = (tid & 3) * 32;
        float sq = __expf(Ls[tr]);
        float sk = __expf(Ls[63] - Ls[tr]);
#pragma unroll
        for (int j = 0; j < 4; ++j) {
            short8 dq = *(const short8*)(Qb + (size_t)tr * KD + seg + j * 8);
            short8 dk = *(const short8*)(Kb + (size_t)tr * KD + seg + j * 8);
            short8 oq;
#pragma unroll
            for (int e = 0; e < 8; ++e) {
                oq[e] = f2bf(bf2f(dq[e]) * sq);
                KT[seg + j * 8 + e][tr] = f2bf(bf2f(dk[e]) * sk);
            }
            int ch = (tid & 3) * 4 + j;
            *(short8*)(Qg + (cb * 64 + tr) * 128 + ((ch ^ (tr & 7)) << 3)) = oq;
        }
    }
    __syncthreads();
    {
        int dk = tid >> 1, seg = (tid & 1) * 32;
#pragma unroll
        for (int j = 0; j < 4; ++j) {
            short8 v = *(const short8*)&KT[dk][seg + j * 8];
            int ch = (tid & 1) * 4 + j;
            *(short8*)(KtT + (cb * 128 + dk) * 64 + ((ch ^ (dk & 7)) << 3)) = v;
        }
    }
}

// ---------------- sequential chunk pass: LDS double-buffered staging ----------------
// (R4: global_load_lds staging + counted vmcnt(16); verified, seq dropped out of top-5)
__global__ __launch_bounds__(256, 1) void seq_kernel(
    const short* __restrict__ UvT, const short* __restrict__ Tk,
    const short* __restrict__ Wb_, const short* __restrict__ Qg,
    const short* __restrict__ KtT, const float* __restrict__ gam63,
    short* __restrict__ ob) {
    extern __shared__ char smem[];
    const int BUF = 65536;
    const int TKO = 0, QGO = 16384, KTO = 32768, UVO = 49152, WO = 57344;
    short (*ST)[136] = (short (*)[136])(smem + 131072);
    short (*UTs)[72] = (short (*)[72])(smem + 131072 + 17408);

    int wg = blockIdx.x;
    int vh = wg & 1, bh = wg >> 1;
    int b = bh >> 4, h = bh & 15;
    int tid = threadIdx.x, wave = tid >> 6, lane = tid & 63;
    int quad = lane >> 4, l16 = lane & 15;
    int swk = l16 & 7;

    for (int i = tid; i < 64 * 136; i += 256) ((short*)(smem + 131072))[i] = 0;
    floatx4 sacc[8];
#pragma unroll
    for (int i = 0; i < 8; ++i) sacc[i] = (floatx4){0.f, 0.f, 0.f, 0.f};

    size_t cb0 = (size_t)bh * NC;
    int row16 = wave * 16 + l16;
    int chq[4];
#pragma unroll
    for (int ks = 0; ks < 4; ++ks) chq[ks] = (((ks * 4 + quad) ^ swk) << 4);
    int uvoff = (((wave * 2 + (quad >> 1)) ^ swk) << 4) + ((quad & 1) << 3);

#define STAGE_CHUNK(bsel_, c_)                                                       \
    {                                                                                \
        char* dst = smem + (bsel_) * BUF;                                            \
        size_t cbs = cb0 + (c_);                                                     \
        const char* gt = (const char*)Tk  + cbs * 16384 + wave * 1024 + lane * 16;   \
        const char* gq = (const char*)Qg  + cbs * 16384 + wave * 1024 + lane * 16;   \
        const char* gk = (const char*)KtT + cbs * 16384 + wave * 1024 + lane * 16;   \
        const char* gu = (const char*)UvT + cbs * 16384 + (size_t)vh * 8192 + wave * 1024 + lane * 16; \
        const char* gw = (const char*)Wb_ + cbs * 8192  + wave * 1024 + lane * 16;   \
        _Pragma("unroll")                                                            \
        for (int it = 0; it < 4; ++it) {                                             \
            load_lds16(gt + it * 4096, dst + TKO + it * 4096 + wave * 1024);         \
            load_lds16(gq + it * 4096, dst + QGO + it * 4096 + wave * 1024);         \
            load_lds16(gk + it * 4096, dst + KTO + it * 4096 + wave * 1024);         \
        }                                                                            \
        _Pragma("unroll")                                                            \
        for (int it = 0; it < 2; ++it) {                                             \
            load_lds16(gu + it * 4096, dst + UVO + it * 4096 + wave * 1024);         \
            load_lds16(gw + it * 4096, dst + WO  + it * 4096 + wave * 1024);         \
        }                                                                            \
    }

    STAGE_CHUNK(0, 0)
    float gamA = gam63[cb0];
    __syncthreads();   // drains stage(0) + ST zero-init, once

#pragma unroll 1
    for (int c = 0; c < NC; ++c) {
        float gamN = 0.f;
        if (c + 1 < NC) {
            gamN = gam63[cb0 + c + 1];
            STAGE_CHUNK((c + 1) & 1, c + 1)
        }
        const char* bufc = smem + (c & 1) * BUF;

        floatx4 uacc[4], oacc[4];
#pragma unroll
        for (int vt = 0; vt < 4; ++vt) {
            short4v u4 = *(const short4v*)(bufc + UVO + (vt * 16 + l16) * 128 + uvoff);
            floatx4 a;
#pragma unroll
            for (int e = 0; e < 4; ++e) a[e] = bf2f(u4[e]);
            uacc[vt] = a;
            oacc[vt] = (floatx4){0.f, 0.f, 0.f, 0.f};
        }
#pragma unroll
        for (int ks = 0; ks < 4; ++ks) {
            short8 tkf = *(const short8*)(bufc + TKO + row16 * 256 + chq[ks]);
            short8 qgf = *(const short8*)(bufc + QGO + row16 * 256 + chq[ks]);
            short8 afT = neg8(tkf);
#pragma unroll
            for (int vt = 0; vt < 4; ++vt) {
                short8 bf = *(const short8*)&ST[vt * 16 + l16][ks * 32 + quad * 8];
                uacc[vt] = MFMA(afT, bf, uacc[vt]);
                oacc[vt] = MFMA(qgf, bf, oacc[vt]);
            }
        }
#pragma unroll
        for (int vt = 0; vt < 4; ++vt) {
            short4v w4;
#pragma unroll
            for (int e = 0; e < 4; ++e) w4[e] = f2bf(uacc[vt][e]);
            *(short4v*)&UTs[vt * 16 + l16][wave * 16 + quad * 4] = w4;
        }
        lds_barrier();
#pragma unroll
        for (int ks = 0; ks < 2; ++ks) {
            short8 wf = *(const short8*)(bufc + WO + row16 * 128 + chq[ks]);
#pragma unroll
            for (int vt = 0; vt < 4; ++vt) {
                short8 bf = *(const short8*)&UTs[vt * 16 + l16][ks * 32 + quad * 8];
                oacc[vt] = MFMA(wf, bf, oacc[vt]);
            }
        }
#pragma unroll
        for (int vt = 0; vt < 4; ++vt)
#pragma unroll
            for (int r = 0; r < 4; ++r) {
                int m = b * S_LEN + c * CT + wave * 16 + quad * 4 + r;
                ob[(size_t)m * VD + h * 128 + vh * 64 + vt * 16 + l16] = f2bf(oacc[vt][r]);
            }
#pragma unroll
        for (int dt = 0; dt < 8; ++dt)
#pragma unroll
            for (int e = 0; e < 4; ++e) sacc[dt][e] *= gamA;
#pragma unroll
        for (int ks = 0; ks < 2; ++ks) {
            short8 af = *(const short8*)&UTs[wave * 16 + l16][ks * 32 + quad * 8];
#pragma unroll
            for (int dt = 0; dt < 8; ++dt) {
                short8 ktf = *(const short8*)(bufc + KTO + (dt * 16 + l16) * 128 + chq[ks]);
                sacc[dt] = MFMA(af, ktf, sacc[dt]);
            }
        }
#pragma unroll
        for (int dt = 0; dt < 8; ++dt)
#pragma unroll
            for (int r = 0; r < 4; ++r)
                ST[wave * 16 + quad * 4 + r][dt * 16 + l16] = f2bf(sacc[dt][r]);

        if (c + 1 < NC) {
            asm volatile("s_waitcnt lgkmcnt(0)" ::: "memory");
            VM(16)      // stage(c+1) drained; ob stores (16 newest) stay in flight
            __builtin_amdgcn_s_barrier();
        }
        gamA = gamN;
    }
#undef STAGE_CHUNK
}

// ---------------- RMSNorm + SiLU gate (bf16 in/out) ----------------
__global__ __launch_bounds__(256) void rms_gate_kernel(
    const short* __restrict__ o, const short* __restrict__ graw,
    const float* __restrict__ nw, short* __restrict__ og) {
    __shared__ float red[4];
    int m = blockIdx.x, t = threadIdx.x;
    short8 a = ((const short8*)(o + (size_t)m * VD))[t];
    float av[8];
#pragma unroll
    for (int i = 0; i < 8; ++i) av[i] = bf2f(a[i]);
    float ss = 0.f;
#pragma unroll
    for (int i = 0; i < 8; ++i) ss += av[i] * av[i];
#pragma unroll
    for (int off = 1; off < 64; off <<= 1) ss += __shfl_xor(ss, off);
    if ((t & 63) == 0) red[t >> 6] = ss;
    __syncthreads();
    float tot = red[0] + red[1] + red[2] + red[3];
    float sc = rsqrtf(tot * (1.f / VD) + 1e-6f);
    short8 gv = ((const short8*)(graw + (size_t)m * VD))[t];
    float4 n0 = ((const float4*)nw)[2 * t];
    float4 n1 = ((const float4*)nw)[2 * t + 1];
    const float* na = (const float*)&n0;
    const float* nb = (const float*)&n1;
    short8 ov;
#pragma unroll
    for (int i = 0; i < 4; ++i) ov[i]     = f2bf(av[i]     * sc * na[i] * silu_f(bf2f(gv[i])));
#pragma unroll
    for (int i = 0; i < 4; ++i) ov[i + 4] = f2bf(av[i + 4] * sc * nb[i] * silu_f(bf2f(gv[i + 4])));
    ((short8*)(og + (size_t)m * VD))[t] = ov;
}

// ---------------- host launcher ----------------
extern "C" void kernel_launch(void* const* d_in, const int* in_sizes, int n_in,
                              void* d_out, int out_size, void* d_ws, size_t ws_size,
                              hipStream_t stream) {
    const float* x    = (const float*)d_in[0];
    const float* Wq   = (const float*)d_in[1];
    const float* Wk   = (const float*)d_in[2];
    const float* Wv   = (const float*)d_in[3];
    const float* Wa   = (const float*)d_in[4];
    const float* Wb   = (const float*)d_in[5];
    const float* Wg   = (const float*)d_in[6];
    const float* Wo   = (const float*)d_in[7];
    const float* cwq  = (const float*)d_in[8];
    const float* cbq  = (const float*)d_in[9];
    const float* cwk  = (const float*)d_in[10];
    const float* cbk  = (const float*)d_in[11];
    const float* cwv  = (const float*)d_in[12];
    const float* cbv  = (const float*)d_in[13];
    const float* Alog = (const float*)d_in[14];
    const float* dtb  = (const float*)d_in[15];
    const float* nw   = (const float*)d_in[16];

    char* ws = (char*)d_ws;
    short* Wob = (short*)(ws);
    short* xb  = (short*)(ws + 8 * MB);
    short* Wqb = (short*)(ws + 24 * MB);
    short* Wkb = (short*)(ws + 32 * MB);
    short* Wvb = (short*)(ws + 40 * MB);
    short* Wgb = (short*)(ws + 48 * MB);
    short* qrb = (short*)(ws + 56 * MB);
    short* krb = (short*)(ws + 72 * MB);
    short* vrb = (short*)(ws + 88 * MB);
    short* grb = (short*)(ws + 104 * MB);
    short* qnb = (short*)(ws + 8 * MB);
    short* knb = (short*)(ws + 24 * MB);
    short* vnb = (short*)(ws + 40 * MB);
    float* gdec = (float*)(ws + 120 * MB);
    float* beta = (float*)(ws + 120 * MB + 262144);
    short* ob  = qrb;   // reuse
    short* ogb = krb;   // reuse
    // chunked-scan buffers
    short* UvT  = (short*)(ws + 121 * MB);   // [1024][128][64]
    short* Tkb  = (short*)(ws + 137 * MB);   // [1024][64][128]
    short* Wbuf = (short*)(ws + 153 * MB);   // [1024][64][64]
    short* Qgb  = (short*)(ws + 161 * MB);   // [1024][64][128]
    short* KtT  = (short*)(ws + 177 * MB);   // [1024][128][64]
    float* gm63 = (float*)(ws + 193 * MB);   // [1024]

    // one-time: allow large dynamic LDS
    static bool attr_done = false;
    if (!attr_done) {
        hipFuncSetAttribute((const void*)gemm8_qkvg,
                            hipFuncAttributeMaxDynamicSharedMemorySize, 131072);
        hipFuncSetAttribute((const void*)gemm_out128,
                            hipFuncAttributeMaxDynamicSharedMemorySize, 98304);
        hipFuncSetAttribute((const void*)seq_kernel,
                            hipFuncAttributeMaxDynamicSharedMemorySize, 157696);
        attr_done = true;
    }

    // 1. fp32 -> bf16 conversions (single launch)
    cvt_all_kernel<<<dim3(4096, 6), 256, 0, stream>>>(x, Wq, Wk, Wv, Wg, Wo,
                                                      xb, Wqb, Wkb, Wvb, Wgb, Wob);

    // 2. a/b projection + decay/beta (coalesced 16-lane-group GEMV, no reg x-cache)
    ab_kernel<<<512, 256, 0, stream>>>(x, Wa, Wb, Alog, dtb, gdec, beta);

    // 3. fused q/k/v/gate projections (256^2 frag-prefetch pipeline, 128 KiB LDS)
    gemm8_qkvg<<<dim3(128, 1, 4), 512, 131072, stream>>>(xb, Wqb, Wkb, Wvb, Wgb,
                                                         qrb, krb, vrb, grb);

    // 4. causal conv + SiLU + l2norm
    conv_kernel<<<16384, 256, 0, stream>>>(qrb, krb, vrb,
                                           cwq, cbq, cwk, cbk, cwv, cbv, qnb, knb, vnb);

    // 5. chunked delta-rule
    solve_kernel<<<2048, 256, 0, stream>>>(knb, vnb, gdec, beta, UvT, Tkb);
    prepb_kernel<<<1024, 256, 0, stream>>>(qnb, knb, gdec, Wbuf, Qgb, KtT, gm63);
    seq_kernel<<<64, 256, 157696, stream>>>(UvT, Tkb, Wbuf, Qgb, KtT, gm63, ob);

    // 6. RMSNorm + SiLU gate
    rms_gate_kernel<<<4096, 256, 0, stream>>>(ob, grb, nw, ogb);

    // 7. output projection (128x256 tile, 256 blocks = 1/CU, fp32 out)
    gemm_out128<<<256, 512, 98304, stream>>>(ogb, Wob, (float*)d_out);
}